// Round 4
// baseline (2446.930 us; speedup 1.0000x reference)
//
#include <hip/hip_runtime.h>
#include <hip/hip_bf16.h>
#include <math.h>

#define N_DIM 1024
#define L_SEQ 16384
#define KS 4

typedef unsigned short ushort_t;
typedef __bf16 bf16x8 __attribute__((ext_vector_type(8)));
typedef float f32x4 __attribute__((ext_vector_type(4)));

#define FW_F32 1
#define FW_SPLIT 2
#define FW_TSPLIT 4
#define FW_ADDD 8
#define FW_MKAB 16

#define AS1 __attribute__((address_space(1)))
#define AS3 __attribute__((address_space(3)))

__device__ __forceinline__ void split2(float v, ushort_t& h, ushort_t& m) {
  union { __bf16 b; ushort_t u; } c;
  __bf16 bh = (__bf16)v;
  float fh = (float)bh;
  c.b = bh; h = c.u;
  c.b = (__bf16)(v - fh); m = c.u;
}

// ---------------- elementwise helpers ----------------

__global__ __launch_bounds__(256) void k_scaleE(float* __restrict__ E,
    const float* __restrict__ A, const float* __restrict__ ls) {
  int i = blockIdx.x * 256 + threadIdx.x;
  float h = 0.5f * expf(ls[0]);
  E[i] = h * A[i];
}

__global__ __launch_bounds__(256) void k_add(float* __restrict__ out,
    const float* __restrict__ a, const float* __restrict__ b) {
  int i = blockIdx.x * 256 + threadIdx.x;
  out[i] = a[i] + b[i];
}

// Bb = step*(B + S@B); write split2 into VT row 0.
__global__ __launch_bounds__(256) void k_bb(ushort_t* __restrict__ VTset,
    const float* __restrict__ S, const float* __restrict__ B,
    const float* __restrict__ ls) {
  const size_t KR = (size_t)128 * N_DIM;
  int row = blockIdx.x * 4 + (threadIdx.x >> 6);
  int lane = threadIdx.x & 63;
  const float* Sr = S + (size_t)row * N_DIM;
  float sum = 0.f;
  for (int k = lane; k < N_DIM; k += 64) sum += Sr[k] * B[k];
  for (int off = 32; off; off >>= 1) sum += __shfl_down(sum, off);
  if (lane == 0) {
    float step = expf(ls[0]);
    float bb = step * (B[row] + sum);
    ushort_t h, m; split2(bb, h, m);
    VTset[row] = h; VTset[KR + row] = m;
  }
}

// W row 0 = split2(C)
__global__ __launch_bounds__(256) void k_initW(ushort_t* __restrict__ Wset,
    const float* __restrict__ Cm) {
  const size_t KR = (size_t)128 * N_DIM;
  int i = blockIdx.x * 256 + threadIdx.x;
  ushort_t h, m; split2(Cm[i], h, m);
  Wset[i] = h; Wset[KR + i] = m;
}

// ------- reduce nparts partials (+D), optional 2v+I, fp32 and/or splits ----
__global__ __launch_bounds__(256) void k_splitred(
    const float* __restrict__ P, int nparts,
    const float* __restrict__ D, float* __restrict__ Cf,
    ushort_t* __restrict__ set, int flags) {
  const size_t NN = (size_t)N_DIM * N_DIM;
  int t = threadIdx.x;
  int r0 = blockIdx.x * 64 + ((t >> 4) << 2);
  int c0 = blockIdx.y * 64 + ((t & 15) << 2);
  float v[4][4];
#pragma unroll
  for (int i = 0; i < 4; ++i) {
    float4 f = *(const float4*)&P[(size_t)(r0 + i) * N_DIM + c0];
    v[i][0] = f.x; v[i][1] = f.y; v[i][2] = f.z; v[i][3] = f.w;
  }
  for (int p = 1; p < nparts; ++p) {
#pragma unroll
    for (int i = 0; i < 4; ++i) {
      float4 f = *(const float4*)&P[p * NN + (size_t)(r0 + i) * N_DIM + c0];
      v[i][0] += f.x; v[i][1] += f.y; v[i][2] += f.z; v[i][3] += f.w;
    }
  }
  if (flags & FW_ADDD) {
#pragma unroll
    for (int i = 0; i < 4; ++i) {
      float4 f = *(const float4*)&D[(size_t)(r0 + i) * N_DIM + c0];
      v[i][0] += f.x; v[i][1] += f.y; v[i][2] += f.z; v[i][3] += f.w;
    }
  }
  if (flags & FW_F32) {
#pragma unroll
    for (int i = 0; i < 4; ++i)
      *(float4*)&Cf[(size_t)(r0 + i) * N_DIM + c0] =
          make_float4(v[i][0], v[i][1], v[i][2], v[i][3]);
  }
  if (flags & FW_MKAB) {
#pragma unroll
    for (int i = 0; i < 4; ++i)
#pragma unroll
      for (int j = 0; j < 4; ++j)
        v[i][j] = 2.0f * v[i][j] + ((r0 + i) == (c0 + j) ? 1.0f : 0.0f);
  }
  if (flags & (FW_SPLIT | FW_TSPLIT)) {
    ushort_t h[4][4], m[4][4];
#pragma unroll
    for (int i = 0; i < 4; ++i)
#pragma unroll
      for (int j = 0; j < 4; ++j) split2(v[i][j], h[i][j], m[i][j]);
    ushort_t* H = set;           ushort_t* M = set + NN;
    ushort_t* HT = set + 2 * NN; ushort_t* MT = set + 3 * NN;
    if (flags & FW_SPLIT) {
#pragma unroll
      for (int i = 0; i < 4; ++i) {
        size_t o = (size_t)(r0 + i) * N_DIM + c0;
        *(ushort4*)&H[o] = make_ushort4(h[i][0], h[i][1], h[i][2], h[i][3]);
        *(ushort4*)&M[o] = make_ushort4(m[i][0], m[i][1], m[i][2], m[i][3]);
      }
    }
    if (flags & FW_TSPLIT) {
#pragma unroll
      for (int j = 0; j < 4; ++j) {
        size_t o = (size_t)(c0 + j) * N_DIM + r0;
        *(ushort4*)&HT[o] = make_ushort4(h[0][j], h[1][j], h[2][j], h[3][j]);
        *(ushort4*)&MT[o] = make_ushort4(m[0][j], m[1][j], m[2][j], m[3][j]);
      }
    }
  }
}

// ---------------- prologue bf16 2-split GEMM, split-K partials -------------
__global__ __launch_bounds__(256) void gemm4(
    const ushort_t* __restrict__ Aset, const ushort_t* __restrict__ Bset,
    float* __restrict__ P, int kChunk) {
  __shared__ __align__(16) ushort_t lds[2][4][2048];
  const size_t NN = (size_t)N_DIM * N_DIM;
  int t = threadIdx.x;
  int m0 = blockIdx.x * 64, n0 = blockIdx.y * 64;
  int kz = blockIdx.z;
  int r = t & 63, kc = t >> 6;

  const ushort_t* gA[2] = {Aset, Aset + NN};
  const ushort_t* gB[2] = {Bset, Bset + NN};
  size_t aoff = (size_t)(m0 + r) * N_DIM + kc * 8 + (size_t)kz * kChunk;
  size_t boff = (size_t)(n0 + r) * N_DIM + kc * 8 + (size_t)kz * kChunk;

  auto stage = [&](int buf, int k0) {
    ushort_t* dst = &lds[buf][0][0];
#pragma unroll
    for (int L = 0; L < 2; ++L) {
      __builtin_amdgcn_global_load_lds(
          (const AS1 void*)(gA[L] + aoff + k0),
          (AS3 void*)(dst + L * 2048 + t * 8), 16, 0, 0);
      __builtin_amdgcn_global_load_lds(
          (const AS1 void*)(gB[L] + boff + k0),
          (AS3 void*)(dst + (2 + L) * 2048 + t * 8), 16, 0, 0);
    }
  };

  f32x4 acc[2][2];
#pragma unroll
  for (int i = 0; i < 2; ++i)
#pragma unroll
    for (int j = 0; j < 2; ++j) acc[i][j] = (f32x4){0.f, 0.f, 0.f, 0.f};

  const int lane = t & 63, w = t >> 6;
  const int wm = (w >> 1) * 32, wn = (w & 1) * 32;
  const int lrow = lane & 15, kg = lane >> 4;
  const int aIdx0 = kg * 512 + (wm + lrow) * 8;
  const int bIdx0 = 2 * 2048 + kg * 512 + (wn + lrow) * 8;

  stage(0, 0);
  __syncthreads();
  int nSteps = kChunk >> 5;
  for (int ks = 0; ks < nSteps; ++ks) {
    int cur = ks & 1;
    if (ks < nSteps - 1) stage(cur ^ 1, (ks + 1) * 32);
    const ushort_t* buf = &lds[cur][0][0];
    bf16x8 a[2][2], b[2][2];
#pragma unroll
    for (int L = 0; L < 2; ++L) {
#pragma unroll
      for (int mi = 0; mi < 2; ++mi)
        a[L][mi] = *(const bf16x8*)&buf[L * 2048 + aIdx0 + mi * 128];
#pragma unroll
      for (int ni = 0; ni < 2; ++ni)
        b[L][ni] = *(const bf16x8*)&buf[bIdx0 + L * 2048 + ni * 128];
    }
#pragma unroll
    for (int mi = 0; mi < 2; ++mi)
#pragma unroll
      for (int ni = 0; ni < 2; ++ni) {
        f32x4 c = acc[mi][ni];
        c = __builtin_amdgcn_mfma_f32_16x16x32_bf16(a[0][mi], b[0][ni], c, 0, 0, 0);
        c = __builtin_amdgcn_mfma_f32_16x16x32_bf16(a[0][mi], b[1][ni], c, 0, 0, 0);
        c = __builtin_amdgcn_mfma_f32_16x16x32_bf16(a[1][mi], b[0][ni], c, 0, 0, 0);
        c = __builtin_amdgcn_mfma_f32_16x16x32_bf16(a[1][mi], b[1][ni], c, 0, 0, 0);
        acc[mi][ni] = c;
      }
    __syncthreads();
  }

  float* Pk = P + (size_t)kz * NN;
#pragma unroll
  for (int mi = 0; mi < 2; ++mi)
#pragma unroll
    for (int ni = 0; ni < 2; ++ni) {
      int rowb = m0 + wm + mi * 16 + kg * 4;
      int col = n0 + wn + ni * 16 + lrow;
#pragma unroll
      for (int j = 0; j < 4; ++j)
        Pk[(size_t)(rowb + j) * N_DIM + col] = acc[mi][ni][j];
    }
}

// ---------------- fused step: squaring(+semaphore reduce) + skinny Krylov --
// Squaring blocks (by<16): P[kz] partial of Q*Q; last block per tile reduces,
// splits, writes Qout {H,M,HT,MT}. Skinny blocks (by==16 or doSquare==0):
// Ka rows [s,2s) = Ka rows [0,s) * Qx, where Qx^T-rows come from Qs row-splits
// (useT=0) or T-splits (useT=1).
__global__ __launch_bounds__(256) void k_step(
    const ushort_t* __restrict__ Qs, ushort_t* __restrict__ Qout,
    float* __restrict__ P, unsigned int* __restrict__ cnt, int epoch,
    ushort_t* __restrict__ Ka, int useT, int s, int doSquare) {
  const size_t NN = (size_t)N_DIM * N_DIM;
  const size_t KR = (size_t)128 * N_DIM;
  __shared__ __align__(16) ushort_t lds[2][4][2048];
  __shared__ unsigned int ov;
  int t = threadIdx.x;
  bool isSk = (!doSquare) || (blockIdx.y == 16);

  if (!isSk) {
    // ---- squaring split-K partial ----
    int m0 = blockIdx.x * 64, n0 = blockIdx.y * 64;
    int kz = blockIdx.z;
    int r = t & 63, kc = t >> 6;
    const ushort_t* gA[2] = {Qs, Qs + NN};
    const ushort_t* gB[2] = {Qs + 2 * NN, Qs + 3 * NN};
    size_t aoff = (size_t)(m0 + r) * N_DIM + kc * 8 + (size_t)kz * 256;
    size_t boff = (size_t)(n0 + r) * N_DIM + kc * 8 + (size_t)kz * 256;

    auto stage = [&](int buf, int k0) {
      ushort_t* dst = &lds[buf][0][0];
#pragma unroll
      for (int L = 0; L < 2; ++L) {
        __builtin_amdgcn_global_load_lds(
            (const AS1 void*)(gA[L] + aoff + k0),
            (AS3 void*)(dst + L * 2048 + t * 8), 16, 0, 0);
        __builtin_amdgcn_global_load_lds(
            (const AS1 void*)(gB[L] + boff + k0),
            (AS3 void*)(dst + (2 + L) * 2048 + t * 8), 16, 0, 0);
      }
    };

    f32x4 acc[2][2];
#pragma unroll
    for (int i = 0; i < 2; ++i)
#pragma unroll
      for (int j = 0; j < 2; ++j) acc[i][j] = (f32x4){0.f, 0.f, 0.f, 0.f};

    const int lane = t & 63, w = t >> 6;
    const int wm = (w >> 1) * 32, wn = (w & 1) * 32;
    const int lrow = lane & 15, kg = lane >> 4;
    const int aIdx0 = kg * 512 + (wm + lrow) * 8;
    const int bIdx0 = 2 * 2048 + kg * 512 + (wn + lrow) * 8;

    stage(0, 0);
    __syncthreads();
    for (int ks = 0; ks < 8; ++ks) {
      int cur = ks & 1;
      if (ks < 7) stage(cur ^ 1, (ks + 1) * 32);
      const ushort_t* buf = &lds[cur][0][0];
      bf16x8 a[2][2], b[2][2];
#pragma unroll
      for (int L = 0; L < 2; ++L) {
#pragma unroll
        for (int mi = 0; mi < 2; ++mi)
          a[L][mi] = *(const bf16x8*)&buf[L * 2048 + aIdx0 + mi * 128];
#pragma unroll
        for (int ni = 0; ni < 2; ++ni)
          b[L][ni] = *(const bf16x8*)&buf[bIdx0 + L * 2048 + ni * 128];
      }
#pragma unroll
      for (int mi = 0; mi < 2; ++mi)
#pragma unroll
        for (int ni = 0; ni < 2; ++ni) {
          f32x4 c = acc[mi][ni];
          c = __builtin_amdgcn_mfma_f32_16x16x32_bf16(a[0][mi], b[0][ni], c, 0, 0, 0);
          c = __builtin_amdgcn_mfma_f32_16x16x32_bf16(a[0][mi], b[1][ni], c, 0, 0, 0);
          c = __builtin_amdgcn_mfma_f32_16x16x32_bf16(a[1][mi], b[0][ni], c, 0, 0, 0);
          c = __builtin_amdgcn_mfma_f32_16x16x32_bf16(a[1][mi], b[1][ni], c, 0, 0, 0);
          acc[mi][ni] = c;
        }
      __syncthreads();
    }

    float* Pk = P + (size_t)blockIdx.z * NN;
#pragma unroll
    for (int mi = 0; mi < 2; ++mi)
#pragma unroll
      for (int ni = 0; ni < 2; ++ni) {
        int rowb = m0 + wm + mi * 16 + kg * 4;
        int col = n0 + wn + ni * 16 + lrow;
#pragma unroll
        for (int j = 0; j < 4; ++j)
          Pk[(size_t)(rowb + j) * N_DIM + col] = acc[mi][ni][j];
      }

    // ---- semaphore: last finisher reduces + splits this 64x64 tile ----
    __threadfence();
    if (t == 0) ov = atomicAdd(&cnt[blockIdx.y * 16 + blockIdx.x], 1u);
    __syncthreads();
    if (ov != (unsigned)(epoch * KS + KS - 1)) return;
    __threadfence();

    int r0 = m0 + ((t >> 4) << 2);
    int c0 = n0 + ((t & 15) << 2);
    float v[4][4];
#pragma unroll
    for (int i = 0; i < 4; ++i) {
      float4 f = *(const float4*)&P[(size_t)(r0 + i) * N_DIM + c0];
      v[i][0] = f.x; v[i][1] = f.y; v[i][2] = f.z; v[i][3] = f.w;
    }
#pragma unroll
    for (int p = 1; p < KS; ++p) {
#pragma unroll
      for (int i = 0; i < 4; ++i) {
        float4 f = *(const float4*)&P[p * NN + (size_t)(r0 + i) * N_DIM + c0];
        v[i][0] += f.x; v[i][1] += f.y; v[i][2] += f.z; v[i][3] += f.w;
      }
    }
    ushort_t h[4][4], m[4][4];
#pragma unroll
    for (int i = 0; i < 4; ++i)
#pragma unroll
      for (int j = 0; j < 4; ++j) split2(v[i][j], h[i][j], m[i][j]);
    ushort_t* H = Qout;           ushort_t* M = Qout + NN;
    ushort_t* HT = Qout + 2 * NN; ushort_t* MT = Qout + 3 * NN;
#pragma unroll
    for (int i = 0; i < 4; ++i) {
      size_t o = (size_t)(r0 + i) * N_DIM + c0;
      *(ushort4*)&H[o] = make_ushort4(h[i][0], h[i][1], h[i][2], h[i][3]);
      *(ushort4*)&M[o] = make_ushort4(m[i][0], m[i][1], m[i][2], m[i][3]);
    }
#pragma unroll
    for (int j = 0; j < 4; ++j) {
      size_t o = (size_t)(c0 + j) * N_DIM + r0;
      *(ushort4*)&HT[o] = make_ushort4(h[0][j], h[1][j], h[2][j], h[3][j]);
      *(ushort4*)&MT[o] = make_ushort4(m[0][j], m[1][j], m[2][j], m[3][j]);
    }
    return;
  }

  // ---- skinny Krylov update ----
  int id = blockIdx.z * 16 + blockIdx.x;  // 0..63
  int rt = id >> 4, ct = id & 15;
  int nRT = (s + 15) >> 4;
  if (rt >= nRT) return;
  const ushort_t* Ah = Ka;
  const ushort_t* Amm = Ka + KR;
  const ushort_t* Bh = Qs + (useT ? 2 * NN : 0);
  const ushort_t* Bm = Bh + NN;
  ushort_t* L = &lds[0][0][0];
  const int lane = t & 63, w = t >> 6;
  const int lrow = lane & 15, kg = lane >> 4;

  auto stageS = [&](int buf, int k0) {
    ushort_t* base = L + buf * 5120;
    if (t < 128) {
      int lvl = t >> 6, rem = t & 63, kcc = rem >> 4, i = rem & 15;
      const ushort_t* src =
          (lvl ? Amm : Ah) + (size_t)(rt * 16 + i) * N_DIM + k0 + kcc * 8;
      __builtin_amdgcn_global_load_lds((const AS1 void*)src,
                                       (AS3 void*)(base + t * 8), 16, 0, 0);
    }
#pragma unroll
    for (int it = 0; it < 2; ++it) {
      int t2 = t + it * 256;
      int lvl = t2 >> 8, rem = t2 & 255, kcc = rem >> 6, c = rem & 63;
      const ushort_t* src =
          (lvl ? Bm : Bh) + (size_t)(ct * 64 + c) * N_DIM + k0 + kcc * 8;
      __builtin_amdgcn_global_load_lds(
          (const AS1 void*)src, (AS3 void*)(base + 1024 + t2 * 8), 16, 0, 0);
    }
  };

  f32x4 acc = (f32x4){0.f, 0.f, 0.f, 0.f};
  const int aO = kg * 128 + lrow * 8;
  const int bO = 1024 + kg * 512 + (w * 16 + lrow) * 8;

  stageS(0, 0);
  __syncthreads();
  for (int ks = 0; ks < 32; ++ks) {
    int cur = ks & 1;
    if (ks < 31) stageS(cur ^ 1, (ks + 1) * 32);
    const ushort_t* b = L + cur * 5120;
    bf16x8 a0 = *(const bf16x8*)&b[aO];
    bf16x8 a1 = *(const bf16x8*)&b[aO + 512];
    bf16x8 b0v = *(const bf16x8*)&b[bO];
    bf16x8 b1v = *(const bf16x8*)&b[bO + 2048];
    acc = __builtin_amdgcn_mfma_f32_16x16x32_bf16(a0, b0v, acc, 0, 0, 0);
    acc = __builtin_amdgcn_mfma_f32_16x16x32_bf16(a0, b1v, acc, 0, 0, 0);
    acc = __builtin_amdgcn_mfma_f32_16x16x32_bf16(a1, b0v, acc, 0, 0, 0);
    acc = __builtin_amdgcn_mfma_f32_16x16x32_bf16(a1, b1v, acc, 0, 0, 0);
    __syncthreads();
  }

  int col = ct * 64 + w * 16 + lrow;
#pragma unroll
  for (int j = 0; j < 4; ++j) {
    int ir = rt * 16 + kg * 4 + j;
    if (ir < s) {
      ushort_t h, m; split2(acc[j], h, m);
      Ka[(size_t)(s + ir) * N_DIM + col] = h;
      Ka[KR + (size_t)(s + ir) * N_DIM + col] = m;
    }
  }
}

// ---------------- combine: Kv[q*128+r] = W[q,:] . V[:,r] -------------------
__global__ __launch_bounds__(256) void k_combine(
    const ushort_t* __restrict__ Wset, const ushort_t* __restrict__ Vset,
    float* __restrict__ Kv) {
  const size_t KR = (size_t)128 * N_DIM;
  __shared__ __align__(16) ushort_t lds[2][5120];
  int t = threadIdx.x;
  int rt = blockIdx.x, ct = blockIdx.y, kz = blockIdx.z;
  int kBase = kz * 256;
  const ushort_t* Ah = Wset;
  const ushort_t* Amm = Wset + KR;
  const ushort_t* Bh = Vset;
  const ushort_t* Bm = Vset + KR;
  ushort_t* L = &lds[0][0];
  const int lane = t & 63, w = t >> 6;
  const int lrow = lane & 15, kg = lane >> 4;

  auto stageS = [&](int buf, int k0) {
    ushort_t* base = L + buf * 5120;
    if (t < 128) {
      int lvl = t >> 6, rem = t & 63, kcc = rem >> 4, i = rem & 15;
      const ushort_t* src =
          (lvl ? Amm : Ah) + (size_t)(rt * 16 + i) * N_DIM + k0 + kcc * 8;
      __builtin_amdgcn_global_load_lds((const AS1 void*)src,
                                       (AS3 void*)(base + t * 8), 16, 0, 0);
    }
#pragma unroll
    for (int it = 0; it < 2; ++it) {
      int t2 = t + it * 256;
      int lvl = t2 >> 8, rem = t2 & 255, kcc = rem >> 6, c = rem & 63;
      const ushort_t* src =
          (lvl ? Bm : Bh) + (size_t)(ct * 64 + c) * N_DIM + k0 + kcc * 8;
      __builtin_amdgcn_global_load_lds(
          (const AS1 void*)src, (AS3 void*)(base + 1024 + t2 * 8), 16, 0, 0);
    }
  };

  f32x4 acc = (f32x4){0.f, 0.f, 0.f, 0.f};
  const int aO = kg * 128 + lrow * 8;
  const int bO = 1024 + kg * 512 + (w * 16 + lrow) * 8;

  stageS(0, kBase);
  __syncthreads();
  for (int ks = 0; ks < 8; ++ks) {
    int cur = ks & 1;
    if (ks < 7) stageS(cur ^ 1, kBase + (ks + 1) * 32);
    const ushort_t* b = L + cur * 5120;
    bf16x8 a0 = *(const bf16x8*)&b[aO];
    bf16x8 a1 = *(const bf16x8*)&b[aO + 512];
    bf16x8 b0v = *(const bf16x8*)&b[bO];
    bf16x8 b1v = *(const bf16x8*)&b[bO + 2048];
    acc = __builtin_amdgcn_mfma_f32_16x16x32_bf16(a0, b0v, acc, 0, 0, 0);
    acc = __builtin_amdgcn_mfma_f32_16x16x32_bf16(a0, b1v, acc, 0, 0, 0);
    acc = __builtin_amdgcn_mfma_f32_16x16x32_bf16(a1, b0v, acc, 0, 0, 0);
    acc = __builtin_amdgcn_mfma_f32_16x16x32_bf16(a1, b1v, acc, 0, 0, 0);
    __syncthreads();
  }

  int rcol = ct * 64 + w * 16 + lrow;
#pragma unroll
  for (int j = 0; j < 4; ++j) {
    int q = rt * 16 + kg * 4 + j;
    atomicAdd(&Kv[q * 128 + rcol], acc[j]);
  }
}

// ---------------- causal convolution --------------------------------------
__global__ __launch_bounds__(256) void conv_k(const float* __restrict__ Kv,
    const float* __restrict__ u, float* __restrict__ y) {
  const int CT = 1024, CJ = 256, LCH = 1024;
  int t0 = blockIdx.x * CT;
  int l0 = blockIdx.y * LCH;
  if (l0 > t0 + CT - 1) return;
  __shared__ __align__(16) float Ks[CJ];
  __shared__ __align__(16) float us[CT + CJ + 8];
  int tid = threadIdx.x;
  float acc0 = 0.f, acc1 = 0.f, acc2 = 0.f, acc3 = 0.f;
  int ltEnd = l0 + LCH; if (ltEnd > t0 + CT) ltEnd = t0 + CT;
  for (int lt = l0; lt < ltEnd; lt += CJ) {
    __syncthreads();
    Ks[tid] = Kv[lt + tid];
    int ub = t0 - lt - (CJ - 1);
    for (int s = tid; s < CT + CJ + 4; s += 256) {
      int g = ub + s;
      us[s] = (g >= 0 && g < L_SEQ) ? u[g] : 0.f;
    }
    __syncthreads();
    const float4* u4 = (const float4*)us;
    float4 wa = u4[tid];
#pragma unroll 4
    for (int jb = 0; jb < CJ / 4; ++jb) {
      float4 wb = u4[tid + jb + 1];
      float4 k4 = *(const float4*)&Ks[CJ - 4 - (jb << 2)];
      acc0 += k4.w * wa.x + k4.z * wa.y + k4.y * wa.z + k4.x * wa.w;
      acc1 += k4.w * wa.y + k4.z * wa.z + k4.y * wa.w + k4.x * wb.x;
      acc2 += k4.w * wa.z + k4.z * wa.w + k4.y * wb.x + k4.x * wb.y;
      acc3 += k4.w * wa.w + k4.z * wb.x + k4.y * wb.y + k4.x * wb.z;
      wa = wb;
    }
  }
  int t = t0 + (tid << 2);
  atomicAdd(&y[t + 0], acc0);
  atomicAdd(&y[t + 1], acc1);
  atomicAdd(&y[t + 2], acc2);
  atomicAdd(&y[t + 3], acc3);
}

// ---------------- host ----------------

extern "C" void kernel_launch(void* const* d_in, const int* in_sizes, int n_in,
                              void* d_out, int out_size, void* d_ws, size_t ws_size,
                              hipStream_t stream) {
  const float* u  = (const float*)d_in[0];
  const float* A  = (const float*)d_in[1];
  const float* B  = (const float*)d_in[2];
  const float* Cm = (const float*)d_in[3];
  const float* ls = (const float*)d_in[4];
  float* y  = (float*)d_out;
  float* ws = (float*)d_ws;

  const int N = N_DIM;
  const size_t NN = (size_t)N * N;
  const size_t KR = (size_t)128 * N;
  float* b0 = ws;                     // E -> S
  float* b1 = b0 + NN;                // E2
  float* b2 = b1 + NN;                // S1
  float* P  = b2 + NN;                // KS partials
  float* Kv = P + (size_t)KS * NN;    // L
  ushort_t* setA = (ushort_t*)(Kv + L_SEQ);
  ushort_t* setB = setA + 4 * NN;
  ushort_t* VTset = setB + 4 * NN;    // {H,M} each 128xN
  ushort_t* Wset = VTset + 2 * KR;
  unsigned int* cnt = (unsigned int*)(Wset + 2 * KR);

  hipMemsetAsync(Kv, 0, (size_t)L_SEQ * sizeof(float), stream);
  hipMemsetAsync(y,  0, (size_t)L_SEQ * sizeof(float), stream);
  hipMemsetAsync(cnt, 0, 256 * sizeof(unsigned int), stream);

  dim3 g16(16, 16);
  dim3 gP(16, 16, KS);
  dim3 gStep(16, 17, KS);
  dim3 gSk(16, 1, KS);

  // E = (step/2)*A ; splits -> setA
  k_scaleE<<<NN / 256, 256, 0, stream>>>(b0, A, ls);
  k_splitred<<<g16, 256, 0, stream>>>(b0, 1, nullptr, nullptr, setA,
                                      FW_SPLIT | FW_TSPLIT);
  // E2 = E*E (fp32 -> b1, T-splits -> setB)
  gemm4<<<gP, 256, 0, stream>>>(setA, setA + 2 * NN, P, N / KS);
  k_splitred<<<g16, 256, 0, stream>>>(P, KS, nullptr, b1, setB,
                                      FW_F32 | FW_TSPLIT);
  // S1 = E + E2 ; row-splits -> setA
  k_add<<<NN / 256, 256, 0, stream>>>(b2, b0, b1);
  k_splitred<<<g16, 256, 0, stream>>>(b2, 1, nullptr, nullptr, setA, FW_SPLIT);
  // S = S1*E2 + S1 (fp32 S -> b0; Ab = 2S+I splits -> setA)
  gemm4<<<gP, 256, 0, stream>>>(setA, setB + 2 * NN, P, N / KS);
  k_splitred<<<g16, 256, 0, stream>>>(P, KS, b2, b0, setA,
                                      FW_F32 | FW_ADDD | FW_MKAB | FW_SPLIT | FW_TSPLIT);
  // VT row0 = split(Bb); W row0 = split(C)
  k_bb<<<256, 256, 0, stream>>>(VTset, b0, B, ls);
  k_initW<<<4, 256, 0, stream>>>(Wset, Cm);

  // 13 fused steps (right j=0..6 on VT, left j=0..5 on W) + final W update.
  ushort_t* cur = setA;
  ushort_t* oth = setB;
  for (int e = 0; e < 13; ++e) {
    int right = (e < 7);
    int s = 1 << (right ? e : (e - 7));
    k_step<<<gStep, 256, 0, stream>>>(cur, oth, P, cnt, e,
                                      right ? VTset : Wset,
                                      right ? 0 : 1, s, 1);
    ushort_t* tmp = cur; cur = oth; oth = tmp;
  }
  k_step<<<gSk, 256, 0, stream>>>(cur, nullptr, P, cnt, 13, Wset, 1, 64, 0);
  // K = W . V
  k_combine<<<dim3(8, 2, KS), 256, 0, stream>>>(Wset, VTset, Kv);
  // y = causal conv(K, u)
  conv_k<<<g16, 256, 0, stream>>>(Kv, u, y);
}

// Round 5
// 739.012 us; speedup vs baseline: 3.3111x; 3.3111x over previous
//
#include <hip/hip_runtime.h>
#include <hip/hip_bf16.h>
#include <math.h>

#define N_DIM 1024
#define L_SEQ 16384

typedef unsigned short ushort_t;
typedef __bf16 bf16x8 __attribute__((ext_vector_type(8)));
typedef float f32x4 __attribute__((ext_vector_type(4)));
typedef float f32x16 __attribute__((ext_vector_type(16)));

#define FW_F32 1
#define FW_SPLIT 2
#define FW_TSPLIT 4
#define FW_ADDD 8
#define FW_MKAB 16

#define AS1 __attribute__((address_space(1)))
#define AS3 __attribute__((address_space(3)))

__device__ __forceinline__ void split2(float v, ushort_t& h, ushort_t& m) {
  union { __bf16 b; ushort_t u; } c;
  __bf16 bh = (__bf16)v;
  float fh = (float)bh;
  c.b = bh; h = c.u;
  c.b = (__bf16)(v - fh); m = c.u;
}

// ---------------- elementwise helpers ----------------

__global__ __launch_bounds__(256) void k_scaleE(float* __restrict__ E,
    const float* __restrict__ A, const float* __restrict__ ls) {
  int i = blockIdx.x * 256 + threadIdx.x;
  float h = 0.5f * expf(ls[0]);
  E[i] = h * A[i];
}

// X -> {H,M,HT,MT} 2-splits
__global__ __launch_bounds__(256) void k_split4(const float* __restrict__ X,
                                                ushort_t* __restrict__ set) {
  const size_t NN = (size_t)N_DIM * N_DIM;
  int t = threadIdx.x;
  int r0 = blockIdx.x * 64 + ((t >> 4) << 2);
  int c0 = blockIdx.y * 64 + ((t & 15) << 2);
  float v[4][4];
#pragma unroll
  for (int i = 0; i < 4; ++i) {
    float4 f = *(const float4*)&X[(size_t)(r0 + i) * N_DIM + c0];
    v[i][0] = f.x; v[i][1] = f.y; v[i][2] = f.z; v[i][3] = f.w;
  }
  ushort_t h[4][4], m[4][4];
#pragma unroll
  for (int i = 0; i < 4; ++i)
#pragma unroll
    for (int j = 0; j < 4; ++j) split2(v[i][j], h[i][j], m[i][j]);
#pragma unroll
  for (int i = 0; i < 4; ++i) {
    size_t o = (size_t)(r0 + i) * N_DIM + c0;
    *(ushort4*)&set[o] = make_ushort4(h[i][0], h[i][1], h[i][2], h[i][3]);
    *(ushort4*)&set[NN + o] = make_ushort4(m[i][0], m[i][1], m[i][2], m[i][3]);
  }
#pragma unroll
  for (int j = 0; j < 4; ++j) {
    size_t o = (size_t)(c0 + j) * N_DIM + r0;
    *(ushort4*)&set[2 * NN + o] = make_ushort4(h[0][j], h[1][j], h[2][j], h[3][j]);
    *(ushort4*)&set[3 * NN + o] = make_ushort4(m[0][j], m[1][j], m[2][j], m[3][j]);
  }
}

// Cf = X + Y ; row-splits -> set{H,M}
__global__ __launch_bounds__(256) void k_addsplit(const float* __restrict__ X,
    const float* __restrict__ Y, float* __restrict__ Cf,
    ushort_t* __restrict__ set) {
  const size_t NN = (size_t)N_DIM * N_DIM;
  int i = (blockIdx.x * 256 + threadIdx.x) * 4;
  float4 a = *(const float4*)&X[i];
  float4 b = *(const float4*)&Y[i];
  float v[4] = {a.x + b.x, a.y + b.y, a.z + b.z, a.w + b.w};
  *(float4*)&Cf[i] = make_float4(v[0], v[1], v[2], v[3]);
  ushort_t h[4], m[4];
#pragma unroll
  for (int k = 0; k < 4; ++k) split2(v[k], h[k], m[k]);
  *(ushort4*)&set[i] = make_ushort4(h[0], h[1], h[2], h[3]);
  *(ushort4*)&set[NN + i] = make_ushort4(m[0], m[1], m[2], m[3]);
}

// Bb = step*(B + S@B); split2 into VT row 0.
__global__ __launch_bounds__(256) void k_bb(ushort_t* __restrict__ VTset,
    const float* __restrict__ S, const float* __restrict__ B,
    const float* __restrict__ ls) {
  const size_t KR = (size_t)128 * N_DIM;
  int row = blockIdx.x * 4 + (threadIdx.x >> 6);
  int lane = threadIdx.x & 63;
  const float* Sr = S + (size_t)row * N_DIM;
  float sum = 0.f;
  for (int k = lane; k < N_DIM; k += 64) sum += Sr[k] * B[k];
  for (int off = 32; off; off >>= 1) sum += __shfl_down(sum, off);
  if (lane == 0) {
    float step = expf(ls[0]);
    float bb = step * (B[row] + sum);
    ushort_t h, m; split2(bb, h, m);
    VTset[row] = h; VTset[KR + row] = m;
  }
}

// W row 0 = split2(C)
__global__ __launch_bounds__(256) void k_initW(ushort_t* __restrict__ Wset,
    const float* __restrict__ Cm) {
  const size_t KR = (size_t)128 * N_DIM;
  int i = blockIdx.x * 256 + threadIdx.x;
  ushort_t h, m; split2(Cm[i], h, m);
  Wset[i] = h; Wset[KR + i] = m;
}

// ---------------- fused step kernel ----------------------------------------
// Squaring blocks (by<32, sqOn): C32x32 tile of Qa*Qb^T-layout product over
// full K=1024; waves k-split; LDS reduce; fused epilogue (+D, f32, mkAb,
// splits, T-splits). No global partials, no fences.
// Skinny blocks (by>=32 or !sqOn): Ka rows [s,2s) = Ka[0,s) * Q (B from SkB).
__global__ __launch_bounds__(256) void k_step(
    const ushort_t* __restrict__ Qa, const ushort_t* __restrict__ Qbt,
    const float* __restrict__ D, float* __restrict__ Cf,
    ushort_t* __restrict__ Oset, int flags,
    const ushort_t* __restrict__ SkB, ushort_t* __restrict__ Ka,
    int s, int sqOn) {
  const size_t NN = (size_t)N_DIM * N_DIM;
  const size_t KR = (size_t)128 * N_DIM;
  __shared__ __align__(16) ushort_t lds[16384];
  int t = threadIdx.x;
  const int lane = t & 63, w = t >> 6;
  bool isSk = (!sqOn) || ((int)blockIdx.y >= 32);

  if (!isSk) {
    int m0 = blockIdx.x * 32, n0 = blockIdx.y * 32;
    // LDS per buf: A[lvl2][ch4][hf2][row32][8] = 4096 us, B same at +4096.
    auto stage = [&](int buf, int k0) {
      ushort_t* dst = lds + buf * 8192;
#pragma unroll
      for (int i = 0; i < 2; ++i) {
        int t2 = t + i * 256;
        int lvl = t2 >> 8, ch = (t2 >> 6) & 3, hf = (t2 >> 5) & 1, row = t2 & 31;
        int gk = k0 + ch * 16 + hf * 8;
        __builtin_amdgcn_global_load_lds(
            (const AS1 void*)(Qa + (size_t)lvl * NN + (size_t)(m0 + row) * N_DIM + gk),
            (AS3 void*)(dst + t2 * 8), 16, 0, 0);
        __builtin_amdgcn_global_load_lds(
            (const AS1 void*)(Qbt + (size_t)lvl * NN + (size_t)(n0 + row) * N_DIM + gk),
            (AS3 void*)(dst + 4096 + t2 * 8), 16, 0, 0);
      }
    };
    f32x16 acc;
#pragma unroll
    for (int j = 0; j < 16; ++j) acc[j] = 0.f;
    const int fo = w * 512 + (lane >> 5) * 256 + (lane & 31) * 8;
    stage(0, 0);
    __syncthreads();
    for (int it = 0; it < 16; ++it) {
      int cur = it & 1;
      if (it < 15) stage(cur ^ 1, (it + 1) * 64);
      const ushort_t* Lb = lds + cur * 8192;
      bf16x8 ah = *(const bf16x8*)&Lb[fo];
      bf16x8 am = *(const bf16x8*)&Lb[fo + 2048];
      bf16x8 bh = *(const bf16x8*)&Lb[4096 + fo];
      bf16x8 bm = *(const bf16x8*)&Lb[4096 + fo + 2048];
      acc = __builtin_amdgcn_mfma_f32_32x32x16_bf16(ah, bh, acc, 0, 0, 0);
      acc = __builtin_amdgcn_mfma_f32_32x32x16_bf16(ah, bm, acc, 0, 0, 0);
      acc = __builtin_amdgcn_mfma_f32_32x32x16_bf16(am, bh, acc, 0, 0, 0);
      acc = __builtin_amdgcn_mfma_f32_32x32x16_bf16(am, bm, acc, 0, 0, 0);
      __syncthreads();
    }
    // cross-wave k-reduction through LDS (reuses buf0, post-barrier)
    float* R = (float*)lds;
#pragma unroll
    for (int j = 0; j < 16; ++j) R[w * 1024 + j * 64 + lane] = acc[j];
    __syncthreads();
    float v[4];
#pragma unroll
    for (int k = 0; k < 4; ++k) {
      int reg = w * 4 + k;
      v[k] = R[reg * 64 + lane] + R[1024 + reg * 64 + lane] +
             R[2048 + reg * 64 + lane] + R[3072 + reg * 64 + lane];
    }
    int col = n0 + (lane & 31);
    int row0 = m0 + 8 * w + 4 * (lane >> 5);
    if (flags & FW_ADDD) {
#pragma unroll
      for (int k = 0; k < 4; ++k) v[k] += D[(size_t)(row0 + k) * N_DIM + col];
    }
    if (flags & FW_F32) {
#pragma unroll
      for (int k = 0; k < 4; ++k) Cf[(size_t)(row0 + k) * N_DIM + col] = v[k];
    }
    if (flags & FW_MKAB) {
#pragma unroll
      for (int k = 0; k < 4; ++k)
        v[k] = 2.f * v[k] + ((row0 + k) == col ? 1.f : 0.f);
    }
    if (flags & (FW_SPLIT | FW_TSPLIT)) {
      ushort_t h[4], m[4];
#pragma unroll
      for (int k = 0; k < 4; ++k) split2(v[k], h[k], m[k]);
      if (flags & FW_SPLIT) {
#pragma unroll
        for (int k = 0; k < 4; ++k) {
          size_t o = (size_t)(row0 + k) * N_DIM + col;
          Oset[o] = h[k]; Oset[NN + o] = m[k];
        }
      }
      if (flags & FW_TSPLIT) {
        size_t o = (size_t)col * N_DIM + row0;
        *(ushort4*)&Oset[2 * NN + o] = make_ushort4(h[0], h[1], h[2], h[3]);
        *(ushort4*)&Oset[3 * NN + o] = make_ushort4(m[0], m[1], m[2], m[3]);
      }
    }
    return;
  }

  // ---- skinny Krylov update ----
  int id = sqOn ? ((int)blockIdx.y - 32) * 32 + (int)blockIdx.x
                : (int)blockIdx.y * 32 + (int)blockIdx.x;
  int rt = id >> 4, ct = id & 15;
  if (rt >= ((s + 15) >> 4)) return;
  const ushort_t* Ah = Ka;
  const ushort_t* Amm = Ka + KR;
  const ushort_t* Bh = SkB;
  const ushort_t* Bm = SkB + NN;
  const int lrow = lane & 15, kg = lane >> 4;

  auto stageS = [&](int buf, int k0) {
    ushort_t* base = lds + buf * 5120;
    if (t < 128) {
      int lvl = t >> 6, rem = t & 63, kcc = rem >> 4, i = rem & 15;
      const ushort_t* src =
          (lvl ? Amm : Ah) + (size_t)(rt * 16 + i) * N_DIM + k0 + kcc * 8;
      __builtin_amdgcn_global_load_lds((const AS1 void*)src,
                                       (AS3 void*)(base + t * 8), 16, 0, 0);
    }
#pragma unroll
    for (int it2 = 0; it2 < 2; ++it2) {
      int t2 = t + it2 * 256;
      int lvl = t2 >> 8, rem = t2 & 255, kcc = rem >> 6, c = rem & 63;
      const ushort_t* src =
          (lvl ? Bm : Bh) + (size_t)(ct * 64 + c) * N_DIM + k0 + kcc * 8;
      __builtin_amdgcn_global_load_lds(
          (const AS1 void*)src, (AS3 void*)(base + 1024 + t2 * 8), 16, 0, 0);
    }
  };

  f32x4 acc = (f32x4){0.f, 0.f, 0.f, 0.f};
  const int aO = kg * 128 + lrow * 8;
  const int bO = 1024 + kg * 512 + (w * 16 + lrow) * 8;

  stageS(0, 0);
  __syncthreads();
  for (int ks2 = 0; ks2 < 32; ++ks2) {
    int cur = ks2 & 1;
    if (ks2 < 31) stageS(cur ^ 1, (ks2 + 1) * 32);
    const ushort_t* b = lds + cur * 5120;
    bf16x8 a0 = *(const bf16x8*)&b[aO];
    bf16x8 a1 = *(const bf16x8*)&b[aO + 512];
    bf16x8 b0v = *(const bf16x8*)&b[bO];
    bf16x8 b1v = *(const bf16x8*)&b[bO + 2048];
    acc = __builtin_amdgcn_mfma_f32_16x16x32_bf16(a0, b0v, acc, 0, 0, 0);
    acc = __builtin_amdgcn_mfma_f32_16x16x32_bf16(a0, b1v, acc, 0, 0, 0);
    acc = __builtin_amdgcn_mfma_f32_16x16x32_bf16(a1, b0v, acc, 0, 0, 0);
    acc = __builtin_amdgcn_mfma_f32_16x16x32_bf16(a1, b1v, acc, 0, 0, 0);
    __syncthreads();
  }

  int col = ct * 64 + w * 16 + lrow;
#pragma unroll
  for (int j = 0; j < 4; ++j) {
    int ir = rt * 16 + kg * 4 + j;
    if (ir < s) {
      ushort_t h, m; split2(acc[j], h, m);
      Ka[(size_t)(s + ir) * N_DIM + col] = h;
      Ka[KR + (size_t)(s + ir) * N_DIM + col] = m;
    }
  }
}

// ---------------- combine: Kv[q*128+r] = W[q,:] . V[:,r] -------------------
__global__ __launch_bounds__(256) void k_combine(
    const ushort_t* __restrict__ Wset, const ushort_t* __restrict__ Vset,
    float* __restrict__ Kv) {
  const size_t KR = (size_t)128 * N_DIM;
  __shared__ __align__(16) ushort_t lds[2][5120];
  int t = threadIdx.x;
  int rt = blockIdx.x, ct = blockIdx.y, kz = blockIdx.z;
  int kBase = kz * 256;
  const ushort_t* Ah = Wset;
  const ushort_t* Amm = Wset + KR;
  const ushort_t* Bh = Vset;
  const ushort_t* Bm = Vset + KR;
  ushort_t* L = &lds[0][0];
  const int lane = t & 63, w = t >> 6;
  const int lrow = lane & 15, kg = lane >> 4;

  auto stageS = [&](int buf, int k0) {
    ushort_t* base = L + buf * 5120;
    if (t < 128) {
      int lvl = t >> 6, rem = t & 63, kcc = rem >> 4, i = rem & 15;
      const ushort_t* src =
          (lvl ? Amm : Ah) + (size_t)(rt * 16 + i) * N_DIM + k0 + kcc * 8;
      __builtin_amdgcn_global_load_lds((const AS1 void*)src,
                                       (AS3 void*)(base + t * 8), 16, 0, 0);
    }
#pragma unroll
    for (int it = 0; it < 2; ++it) {
      int t2 = t + it * 256;
      int lvl = t2 >> 8, rem = t2 & 255, kcc = rem >> 6, c = rem & 63;
      const ushort_t* src =
          (lvl ? Bm : Bh) + (size_t)(ct * 64 + c) * N_DIM + k0 + kcc * 8;
      __builtin_amdgcn_global_load_lds(
          (const AS1 void*)src, (AS3 void*)(base + 1024 + t2 * 8), 16, 0, 0);
    }
  };

  f32x4 acc = (f32x4){0.f, 0.f, 0.f, 0.f};
  const int aO = kg * 128 + lrow * 8;
  const int bO = 1024 + kg * 512 + (w * 16 + lrow) * 8;

  stageS(0, kBase);
  __syncthreads();
  for (int ks = 0; ks < 8; ++ks) {
    int cur = ks & 1;
    if (ks < 7) stageS(cur ^ 1, kBase + (ks + 1) * 32);
    const ushort_t* b = L + cur * 5120;
    bf16x8 a0 = *(const bf16x8*)&b[aO];
    bf16x8 a1 = *(const bf16x8*)&b[aO + 512];
    bf16x8 b0v = *(const bf16x8*)&b[bO];
    bf16x8 b1v = *(const bf16x8*)&b[bO + 2048];
    acc = __builtin_amdgcn_mfma_f32_16x16x32_bf16(a0, b0v, acc, 0, 0, 0);
    acc = __builtin_amdgcn_mfma_f32_16x16x32_bf16(a0, b1v, acc, 0, 0, 0);
    acc = __builtin_amdgcn_mfma_f32_16x16x32_bf16(a1, b0v, acc, 0, 0, 0);
    acc = __builtin_amdgcn_mfma_f32_16x16x32_bf16(a1, b1v, acc, 0, 0, 0);
    __syncthreads();
  }

  int rcol = ct * 64 + w * 16 + lrow;
#pragma unroll
  for (int j = 0; j < 4; ++j) {
    int q = rt * 16 + kg * 4 + j;
    atomicAdd(&Kv[q * 128 + rcol], acc[j]);
  }
}

// ---------------- causal convolution --------------------------------------
__global__ __launch_bounds__(256) void conv_k(const float* __restrict__ Kv,
    const float* __restrict__ u, float* __restrict__ y) {
  const int CT = 1024, CJ = 256, LCH = 1024;
  int t0 = blockIdx.x * CT;
  int l0 = blockIdx.y * LCH;
  if (l0 > t0 + CT - 1) return;
  __shared__ __align__(16) float Ks[CJ];
  __shared__ __align__(16) float us[CT + CJ + 8];
  int tid = threadIdx.x;
  float acc0 = 0.f, acc1 = 0.f, acc2 = 0.f, acc3 = 0.f;
  int ltEnd = l0 + LCH; if (ltEnd > t0 + CT) ltEnd = t0 + CT;
  for (int lt = l0; lt < ltEnd; lt += CJ) {
    __syncthreads();
    Ks[tid] = Kv[lt + tid];
    int ub = t0 - lt - (CJ - 1);
    for (int s = tid; s < CT + CJ + 4; s += 256) {
      int g = ub + s;
      us[s] = (g >= 0 && g < L_SEQ) ? u[g] : 0.f;
    }
    __syncthreads();
    const float4* u4 = (const float4*)us;
    float4 wa = u4[tid];
#pragma unroll 4
    for (int jb = 0; jb < CJ / 4; ++jb) {
      float4 wb = u4[tid + jb + 1];
      float4 k4 = *(const float4*)&Ks[CJ - 4 - (jb << 2)];
      acc0 += k4.w * wa.x + k4.z * wa.y + k4.y * wa.z + k4.x * wa.w;
      acc1 += k4.w * wa.y + k4.z * wa.z + k4.y * wa.w + k4.x * wb.x;
      acc2 += k4.w * wa.z + k4.z * wa.w + k4.y * wb.x + k4.x * wb.y;
      acc3 += k4.w * wa.w + k4.z * wb.x + k4.y * wb.y + k4.x * wb.z;
      wa = wb;
    }
  }
  int t = t0 + (tid << 2);
  atomicAdd(&y[t + 0], acc0);
  atomicAdd(&y[t + 1], acc1);
  atomicAdd(&y[t + 2], acc2);
  atomicAdd(&y[t + 3], acc3);
}

// ---------------- host ----------------

extern "C" void kernel_launch(void* const* d_in, const int* in_sizes, int n_in,
                              void* d_out, int out_size, void* d_ws, size_t ws_size,
                              hipStream_t stream) {
  const float* u  = (const float*)d_in[0];
  const float* A  = (const float*)d_in[1];
  const float* B  = (const float*)d_in[2];
  const float* Cm = (const float*)d_in[3];
  const float* ls = (const float*)d_in[4];
  float* y  = (float*)d_out;
  float* ws = (float*)d_ws;

  const int N = N_DIM;
  const size_t NN = (size_t)N * N;
  const size_t KR = (size_t)128 * N;
  float* b0 = ws;                     // E -> S
  float* b1 = b0 + NN;                // E2
  float* b2 = b1 + NN;                // S1
  float* Kv = b2 + NN;                // 128*128
  ushort_t* setA = (ushort_t*)(Kv + L_SEQ);
  ushort_t* setB = setA + 4 * NN;
  ushort_t* setC = setB + 4 * NN;
  ushort_t* VTset = setC + 4 * NN;    // {H,M} each 128xN
  ushort_t* Wset = VTset + 2 * KR;

  hipMemsetAsync(Kv, 0, (size_t)L_SEQ * sizeof(float), stream);
  hipMemsetAsync(y,  0, (size_t)L_SEQ * sizeof(float), stream);

  dim3 gSq(32, 32), gFull(32, 34), gSk(32, 2);

  // E = (step/2)*A ; 4-plane splits -> setA
  k_scaleE<<<NN / 256, 256, 0, stream>>>(b0, A, ls);
  k_split4<<<dim3(16, 16), 256, 0, stream>>>(b0, setA);
  // E2 = E*E : f32 -> b1, T-splits -> setB
  k_step<<<gSq, 256, 0, stream>>>(setA, setA + 2 * NN, nullptr, b1, setB,
                                  FW_F32 | FW_TSPLIT, nullptr, nullptr, 0, 1);
  // S1 = E + E2 : f32 -> b2, row-splits -> setA
  k_addsplit<<<NN / 1024, 256, 0, stream>>>(b0, b1, b2, setA);
  // S = S1*E2 + S1 : f32 S -> b0; Ab=2S+I splits -> setC
  k_step<<<gSq, 256, 0, stream>>>(setA, setB + 2 * NN, b2, b0, setC,
                                  FW_ADDD | FW_F32 | FW_MKAB | FW_SPLIT | FW_TSPLIT,
                                  nullptr, nullptr, 0, 1);
  // VT row0 = split(Bb); W row0 = split(C)
  k_bb<<<256, 256, 0, stream>>>(VTset, b0, B, ls);
  k_initW<<<4, 256, 0, stream>>>(Wset, Cm);

  // 13 fused steps: squaring Q_e -> Q_{e+1} + skinny Krylov using Q_e.
  ushort_t* cur = setC;
  ushort_t* oth = setA;
  for (int e = 0; e < 13; ++e) {
    int right = (e < 7);
    int s = 1 << (right ? e : (e - 7));
    k_step<<<gFull, 256, 0, stream>>>(cur, cur + 2 * NN, nullptr, nullptr, oth,
                                      FW_SPLIT | FW_TSPLIT,
                                      right ? cur : cur + 2 * NN,
                                      right ? VTset : Wset, s, 1);
    ushort_t* tmp = cur; cur = oth; oth = tmp;
  }
  // final skinny-only: W rows 64->128 with Q_13
  k_step<<<gSk, 256, 0, stream>>>(cur, cur + 2 * NN, nullptr, nullptr, nullptr,
                                  0, cur + 2 * NN, Wset, 64, 0);
  // K = W . V
  k_combine<<<dim3(8, 2, 4), 256, 0, stream>>>(Wset, VTset, Kv);
  // y = causal conv(K, u)
  conv_k<<<dim3(16, 16), 256, 0, stream>>>(Kv, u, y);
}

// Round 6
// 629.458 us; speedup vs baseline: 3.8874x; 1.1740x over previous
//
#include <hip/hip_runtime.h>
#include <hip/hip_bf16.h>
#include <math.h>

#define N_DIM 1024
#define L_SEQ 16384
#define KS 4

typedef unsigned short ushort_t;
typedef __bf16 bf16x8 __attribute__((ext_vector_type(8)));
typedef float f32x4 __attribute__((ext_vector_type(4)));

#define FW_F32 1
#define FW_SPLIT 2
#define FW_TSPLIT 4
#define FW_ADDD 8
#define FW_MKAB 16

#define AS1 __attribute__((address_space(1)))
#define AS3 __attribute__((address_space(3)))

__device__ __forceinline__ void split2(float v, ushort_t& h, ushort_t& m) {
  union { __bf16 b; ushort_t u; } c;
  __bf16 bh = (__bf16)v;
  float fh = (float)bh;
  c.b = bh; h = c.u;
  c.b = (__bf16)(v - fh); m = c.u;
}

// ---------------- fused scale + 4-plane split: E = h*A -------------------
__global__ __launch_bounds__(256) void k_scalesplit(const float* __restrict__ A,
    const float* __restrict__ ls, float* __restrict__ E,
    ushort_t* __restrict__ set) {
  const size_t NN = (size_t)N_DIM * N_DIM;
  float hs = 0.5f * expf(ls[0]);
  int t = threadIdx.x;
  int r0 = blockIdx.x * 64 + ((t >> 4) << 2);
  int c0 = blockIdx.y * 64 + ((t & 15) << 2);
  float v[4][4];
#pragma unroll
  for (int i = 0; i < 4; ++i) {
    float4 f = *(const float4*)&A[(size_t)(r0 + i) * N_DIM + c0];
    v[i][0] = hs * f.x; v[i][1] = hs * f.y; v[i][2] = hs * f.z; v[i][3] = hs * f.w;
    *(float4*)&E[(size_t)(r0 + i) * N_DIM + c0] =
        make_float4(v[i][0], v[i][1], v[i][2], v[i][3]);
  }
  ushort_t h[4][4], m[4][4];
#pragma unroll
  for (int i = 0; i < 4; ++i)
#pragma unroll
    for (int j = 0; j < 4; ++j) split2(v[i][j], h[i][j], m[i][j]);
#pragma unroll
  for (int i = 0; i < 4; ++i) {
    size_t o = (size_t)(r0 + i) * N_DIM + c0;
    *(ushort4*)&set[o] = make_ushort4(h[i][0], h[i][1], h[i][2], h[i][3]);
    *(ushort4*)&set[NN + o] = make_ushort4(m[i][0], m[i][1], m[i][2], m[i][3]);
  }
#pragma unroll
  for (int j = 0; j < 4; ++j) {
    size_t o = (size_t)(c0 + j) * N_DIM + r0;
    *(ushort4*)&set[2 * NN + o] = make_ushort4(h[0][j], h[1][j], h[2][j], h[3][j]);
    *(ushort4*)&set[3 * NN + o] = make_ushort4(m[0][j], m[1][j], m[2][j], m[3][j]);
  }
}

// Cf = X + Y ; row-splits -> set{H,M}
__global__ __launch_bounds__(256) void k_addsplit(const float* __restrict__ X,
    const float* __restrict__ Y, float* __restrict__ Cf,
    ushort_t* __restrict__ set) {
  const size_t NN = (size_t)N_DIM * N_DIM;
  int i = (blockIdx.x * 256 + threadIdx.x) * 4;
  float4 a = *(const float4*)&X[i];
  float4 b = *(const float4*)&Y[i];
  float v[4] = {a.x + b.x, a.y + b.y, a.z + b.z, a.w + b.w};
  *(float4*)&Cf[i] = make_float4(v[0], v[1], v[2], v[3]);
  ushort_t h[4], m[4];
#pragma unroll
  for (int k = 0; k < 4; ++k) split2(v[k], h[k], m[k]);
  *(ushort4*)&set[i] = make_ushort4(h[0], h[1], h[2], h[3]);
  *(ushort4*)&set[NN + i] = make_ushort4(m[0], m[1], m[2], m[3]);
}

// Bb = step*(B + S@B); split2 into VT row 0.
__global__ __launch_bounds__(256) void k_bb(ushort_t* __restrict__ VTset,
    const float* __restrict__ S, const float* __restrict__ B,
    const float* __restrict__ ls) {
  const size_t KR = (size_t)128 * N_DIM;
  int row = blockIdx.x * 4 + (threadIdx.x >> 6);
  int lane = threadIdx.x & 63;
  const float* Sr = S + (size_t)row * N_DIM;
  float sum = 0.f;
  for (int k = lane; k < N_DIM; k += 64) sum += Sr[k] * B[k];
  for (int off = 32; off; off >>= 1) sum += __shfl_down(sum, off);
  if (lane == 0) {
    float step = expf(ls[0]);
    float bb = step * (B[row] + sum);
    ushort_t h, m; split2(bb, h, m);
    VTset[row] = h; VTset[KR + row] = m;
  }
}

// W row 0 = split2(C)
__global__ __launch_bounds__(256) void k_initW(ushort_t* __restrict__ Wset,
    const float* __restrict__ Cm) {
  const size_t KR = (size_t)128 * N_DIM;
  int i = blockIdx.x * 256 + threadIdx.x;
  ushort_t h, m; split2(Cm[i], h, m);
  Wset[i] = h; Wset[KR + i] = m;
}

// ------- reduce KS partials (+D), optional mkAb, fp32 and/or splits --------
__global__ __launch_bounds__(256) void k_splitred(
    const float* __restrict__ P,
    const float* __restrict__ D, float* __restrict__ Cf,
    ushort_t* __restrict__ set, int flags) {
  const size_t NN = (size_t)N_DIM * N_DIM;
  int t = threadIdx.x;
  int r0 = blockIdx.x * 64 + ((t >> 4) << 2);
  int c0 = blockIdx.y * 64 + ((t & 15) << 2);
  float v[4][4];
#pragma unroll
  for (int i = 0; i < 4; ++i) {
    float4 f = *(const float4*)&P[(size_t)(r0 + i) * N_DIM + c0];
    v[i][0] = f.x; v[i][1] = f.y; v[i][2] = f.z; v[i][3] = f.w;
  }
#pragma unroll
  for (int p = 1; p < KS; ++p) {
#pragma unroll
    for (int i = 0; i < 4; ++i) {
      float4 f = *(const float4*)&P[p * NN + (size_t)(r0 + i) * N_DIM + c0];
      v[i][0] += f.x; v[i][1] += f.y; v[i][2] += f.z; v[i][3] += f.w;
    }
  }
  if (flags & FW_ADDD) {
#pragma unroll
    for (int i = 0; i < 4; ++i) {
      float4 f = *(const float4*)&D[(size_t)(r0 + i) * N_DIM + c0];
      v[i][0] += f.x; v[i][1] += f.y; v[i][2] += f.z; v[i][3] += f.w;
    }
  }
  if (flags & FW_F32) {
#pragma unroll
    for (int i = 0; i < 4; ++i)
      *(float4*)&Cf[(size_t)(r0 + i) * N_DIM + c0] =
          make_float4(v[i][0], v[i][1], v[i][2], v[i][3]);
  }
  if (flags & FW_MKAB) {
#pragma unroll
    for (int i = 0; i < 4; ++i)
#pragma unroll
      for (int j = 0; j < 4; ++j)
        v[i][j] = 2.0f * v[i][j] + ((r0 + i) == (c0 + j) ? 1.0f : 0.0f);
  }
  if (flags & (FW_SPLIT | FW_TSPLIT)) {
    ushort_t h[4][4], m[4][4];
#pragma unroll
    for (int i = 0; i < 4; ++i)
#pragma unroll
      for (int j = 0; j < 4; ++j) split2(v[i][j], h[i][j], m[i][j]);
    if (flags & FW_SPLIT) {
#pragma unroll
      for (int i = 0; i < 4; ++i) {
        size_t o = (size_t)(r0 + i) * N_DIM + c0;
        *(ushort4*)&set[o] = make_ushort4(h[i][0], h[i][1], h[i][2], h[i][3]);
        *(ushort4*)&set[NN + o] = make_ushort4(m[i][0], m[i][1], m[i][2], m[i][3]);
      }
    }
    if (flags & FW_TSPLIT) {
#pragma unroll
      for (int j = 0; j < 4; ++j) {
        size_t o = (size_t)(c0 + j) * N_DIM + r0;
        *(ushort4*)&set[2 * NN + o] = make_ushort4(h[0][j], h[1][j], h[2][j], h[3][j]);
        *(ushort4*)&set[3 * NN + o] = make_ushort4(m[0][j], m[1][j], m[2][j], m[3][j]);
      }
    }
  }
}

// ---------------- fused: split-K squaring partials + skinny Krylov ---------
// z<4 (sqOn): 64x64 tile, kChunk=256 -> P[z].  z==4 (or !sqOn): skinny
// Ka rows [s,2s) = Ka[0,s) * Qx (B^T rows from SkB planes).
__global__ __launch_bounds__(256) void gemm4f(
    const ushort_t* __restrict__ Qa, const ushort_t* __restrict__ Qbt,
    float* __restrict__ P, const ushort_t* __restrict__ SkB,
    ushort_t* __restrict__ Ka, int s, int sqOn) {
  const size_t NN = (size_t)N_DIM * N_DIM;
  const size_t KR = (size_t)128 * N_DIM;
  __shared__ __align__(16) ushort_t lds[16384];
  int t = threadIdx.x;
  const int lane = t & 63, w = t >> 6;
  bool isSk = (!sqOn) || ((int)blockIdx.z >= 4);

  if (!isSk) {
    int m0 = blockIdx.x * 64, n0 = blockIdx.y * 64;
    int kz = blockIdx.z;
    int r = t & 63, kc = t >> 6;
    const ushort_t* gA[2] = {Qa, Qa + NN};
    const ushort_t* gB[2] = {Qbt, Qbt + NN};
    size_t aoff = (size_t)(m0 + r) * N_DIM + kc * 8 + (size_t)kz * 256;
    size_t boff = (size_t)(n0 + r) * N_DIM + kc * 8 + (size_t)kz * 256;

    auto stage = [&](int buf, int k0) {
      ushort_t* dst = lds + buf * 8192;
#pragma unroll
      for (int L = 0; L < 2; ++L) {
        __builtin_amdgcn_global_load_lds(
            (const AS1 void*)(gA[L] + aoff + k0),
            (AS3 void*)(dst + L * 2048 + t * 8), 16, 0, 0);
        __builtin_amdgcn_global_load_lds(
            (const AS1 void*)(gB[L] + boff + k0),
            (AS3 void*)(dst + (2 + L) * 2048 + t * 8), 16, 0, 0);
      }
    };

    f32x4 acc[2][2];
#pragma unroll
    for (int i = 0; i < 2; ++i)
#pragma unroll
      for (int j = 0; j < 2; ++j) acc[i][j] = (f32x4){0.f, 0.f, 0.f, 0.f};

    const int wm = (w >> 1) * 32, wn = (w & 1) * 32;
    const int lrow = lane & 15, kg = lane >> 4;
    const int aIdx0 = kg * 512 + (wm + lrow) * 8;
    const int bIdx0 = 2 * 2048 + kg * 512 + (wn + lrow) * 8;

    stage(0, 0);
    __syncthreads();
    for (int ks = 0; ks < 8; ++ks) {
      int cur = ks & 1;
      if (ks < 7) stage(cur ^ 1, (ks + 1) * 32);
      const ushort_t* buf = lds + cur * 8192;
      bf16x8 a[2][2], b[2][2];
#pragma unroll
      for (int L = 0; L < 2; ++L) {
#pragma unroll
        for (int mi = 0; mi < 2; ++mi)
          a[L][mi] = *(const bf16x8*)&buf[L * 2048 + aIdx0 + mi * 128];
#pragma unroll
        for (int ni = 0; ni < 2; ++ni)
          b[L][ni] = *(const bf16x8*)&buf[bIdx0 + L * 2048 + ni * 128];
      }
#pragma unroll
      for (int mi = 0; mi < 2; ++mi)
#pragma unroll
        for (int ni = 0; ni < 2; ++ni) {
          f32x4 c = acc[mi][ni];
          c = __builtin_amdgcn_mfma_f32_16x16x32_bf16(a[0][mi], b[0][ni], c, 0, 0, 0);
          c = __builtin_amdgcn_mfma_f32_16x16x32_bf16(a[0][mi], b[1][ni], c, 0, 0, 0);
          c = __builtin_amdgcn_mfma_f32_16x16x32_bf16(a[1][mi], b[0][ni], c, 0, 0, 0);
          c = __builtin_amdgcn_mfma_f32_16x16x32_bf16(a[1][mi], b[1][ni], c, 0, 0, 0);
          acc[mi][ni] = c;
        }
      __syncthreads();
    }

    float* Pk = P + (size_t)kz * NN;
#pragma unroll
    for (int mi = 0; mi < 2; ++mi)
#pragma unroll
      for (int ni = 0; ni < 2; ++ni) {
        int rowb = m0 + wm + mi * 16 + kg * 4;
        int col = n0 + wn + ni * 16 + lrow;
#pragma unroll
        for (int j = 0; j < 4; ++j)
          Pk[(size_t)(rowb + j) * N_DIM + col] = acc[mi][ni][j];
      }
    return;
  }

  // ---- skinny Krylov update ----
  int id = blockIdx.y * 16 + blockIdx.x;
  if (id >= 64) return;
  int rt = id >> 4, ct = id & 15;
  if (rt >= ((s + 15) >> 4)) return;
  const ushort_t* Ah = Ka;
  const ushort_t* Amm = Ka + KR;
  const ushort_t* Bh = SkB;
  const ushort_t* Bm = SkB + NN;
  const int lrow = lane & 15, kg = lane >> 4;

  auto stageS = [&](int buf, int k0) {
    ushort_t* base = lds + buf * 5120;
    if (t < 128) {
      int lvl = t >> 6, rem = t & 63, kcc = rem >> 4, i = rem & 15;
      const ushort_t* src =
          (lvl ? Amm : Ah) + (size_t)(rt * 16 + i) * N_DIM + k0 + kcc * 8;
      __builtin_amdgcn_global_load_lds((const AS1 void*)src,
                                       (AS3 void*)(base + t * 8), 16, 0, 0);
    }
#pragma unroll
    for (int it2 = 0; it2 < 2; ++it2) {
      int t2 = t + it2 * 256;
      int lvl = t2 >> 8, rem = t2 & 255, kcc = rem >> 6, c = rem & 63;
      const ushort_t* src =
          (lvl ? Bm : Bh) + (size_t)(ct * 64 + c) * N_DIM + k0 + kcc * 8;
      __builtin_amdgcn_global_load_lds(
          (const AS1 void*)src, (AS3 void*)(base + 1024 + t2 * 8), 16, 0, 0);
    }
  };

  f32x4 acc = (f32x4){0.f, 0.f, 0.f, 0.f};
  const int aO = kg * 128 + lrow * 8;
  const int bO = 1024 + kg * 512 + (w * 16 + lrow) * 8;

  stageS(0, 0);
  __syncthreads();
  for (int ks2 = 0; ks2 < 32; ++ks2) {
    int cur = ks2 & 1;
    if (ks2 < 31) stageS(cur ^ 1, (ks2 + 1) * 32);
    const ushort_t* b = lds + cur * 5120;
    bf16x8 a0 = *(const bf16x8*)&b[aO];
    bf16x8 a1 = *(const bf16x8*)&b[aO + 512];
    bf16x8 b0v = *(const bf16x8*)&b[bO];
    bf16x8 b1v = *(const bf16x8*)&b[bO + 2048];
    acc = __builtin_amdgcn_mfma_f32_16x16x32_bf16(a0, b0v, acc, 0, 0, 0);
    acc = __builtin_amdgcn_mfma_f32_16x16x32_bf16(a0, b1v, acc, 0, 0, 0);
    acc = __builtin_amdgcn_mfma_f32_16x16x32_bf16(a1, b0v, acc, 0, 0, 0);
    acc = __builtin_amdgcn_mfma_f32_16x16x32_bf16(a1, b1v, acc, 0, 0, 0);
    __syncthreads();
  }

  int col = ct * 64 + w * 16 + lrow;
#pragma unroll
  for (int j = 0; j < 4; ++j) {
    int ir = rt * 16 + kg * 4 + j;
    if (ir < s) {
      ushort_t h, m; split2(acc[j], h, m);
      Ka[(size_t)(s + ir) * N_DIM + col] = h;
      Ka[KR + (size_t)(s + ir) * N_DIM + col] = m;
    }
  }
}

// ---------------- combine: Kv[q*128+r] = W[q,:] . V[:,r] -------------------
__global__ __launch_bounds__(256) void k_combine(
    const ushort_t* __restrict__ Wset, const ushort_t* __restrict__ Vset,
    float* __restrict__ Kv) {
  const size_t KR = (size_t)128 * N_DIM;
  __shared__ __align__(16) ushort_t lds[2][5120];
  int t = threadIdx.x;
  int rt = blockIdx.x, ct = blockIdx.y, kz = blockIdx.z;
  int kBase = kz * 256;
  const ushort_t* Ah = Wset;
  const ushort_t* Amm = Wset + KR;
  const ushort_t* Bh = Vset;
  const ushort_t* Bm = Vset + KR;
  ushort_t* L = &lds[0][0];
  const int lane = t & 63, w = t >> 6;
  const int lrow = lane & 15, kg = lane >> 4;

  auto stageS = [&](int buf, int k0) {
    ushort_t* base = L + buf * 5120;
    if (t < 128) {
      int lvl = t >> 6, rem = t & 63, kcc = rem >> 4, i = rem & 15;
      const ushort_t* src =
          (lvl ? Amm : Ah) + (size_t)(rt * 16 + i) * N_DIM + k0 + kcc * 8;
      __builtin_amdgcn_global_load_lds((const AS1 void*)src,
                                       (AS3 void*)(base + t * 8), 16, 0, 0);
    }
#pragma unroll
    for (int it = 0; it < 2; ++it) {
      int t2 = t + it * 256;
      int lvl = t2 >> 8, rem = t2 & 255, kcc = rem >> 6, c = rem & 63;
      const ushort_t* src =
          (lvl ? Bm : Bh) + (size_t)(ct * 64 + c) * N_DIM + k0 + kcc * 8;
      __builtin_amdgcn_global_load_lds(
          (const AS1 void*)src, (AS3 void*)(base + 1024 + t2 * 8), 16, 0, 0);
    }
  };

  f32x4 acc = (f32x4){0.f, 0.f, 0.f, 0.f};
  const int aO = kg * 128 + lrow * 8;
  const int bO = 1024 + kg * 512 + (w * 16 + lrow) * 8;

  stageS(0, kBase);
  __syncthreads();
  for (int ks = 0; ks < 8; ++ks) {
    int cur = ks & 1;
    if (ks < 7) stageS(cur ^ 1, kBase + (ks + 1) * 32);
    const ushort_t* b = L + cur * 5120;
    bf16x8 a0 = *(const bf16x8*)&b[aO];
    bf16x8 a1 = *(const bf16x8*)&b[aO + 512];
    bf16x8 b0v = *(const bf16x8*)&b[bO];
    bf16x8 b1v = *(const bf16x8*)&b[bO + 2048];
    acc = __builtin_amdgcn_mfma_f32_16x16x32_bf16(a0, b0v, acc, 0, 0, 0);
    acc = __builtin_amdgcn_mfma_f32_16x16x32_bf16(a0, b1v, acc, 0, 0, 0);
    acc = __builtin_amdgcn_mfma_f32_16x16x32_bf16(a1, b0v, acc, 0, 0, 0);
    acc = __builtin_amdgcn_mfma_f32_16x16x32_bf16(a1, b1v, acc, 0, 0, 0);
    __syncthreads();
  }

  int rcol = ct * 64 + w * 16 + lrow;
#pragma unroll
  for (int j = 0; j < 4; ++j) {
    int q = rt * 16 + kg * 4 + j;
    atomicAdd(&Kv[q * 128 + rcol], acc[j]);
  }
}

// ---------------- causal convolution --------------------------------------
__global__ __launch_bounds__(256) void conv_k(const float* __restrict__ Kv,
    const float* __restrict__ u, float* __restrict__ y) {
  const int CT = 1024, CJ = 256, LCH = 1024;
  int t0 = blockIdx.x * CT;
  int l0 = blockIdx.y * LCH;
  if (l0 > t0 + CT - 1) return;
  __shared__ __align__(16) float Ks[CJ];
  __shared__ __align__(16) float us[CT + CJ + 8];
  int tid = threadIdx.x;
  float acc0 = 0.f, acc1 = 0.f, acc2 = 0.f, acc3 = 0.f;
  int ltEnd = l0 + LCH; if (ltEnd > t0 + CT) ltEnd = t0 + CT;
  for (int lt = l0; lt < ltEnd; lt += CJ) {
    __syncthreads();
    Ks[tid] = Kv[lt + tid];
    int ub = t0 - lt - (CJ - 1);
    for (int s = tid; s < CT + CJ + 4; s += 256) {
      int g = ub + s;
      us[s] = (g >= 0 && g < L_SEQ) ? u[g] : 0.f;
    }
    __syncthreads();
    const float4* u4 = (const float4*)us;
    float4 wa = u4[tid];
#pragma unroll 4
    for (int jb = 0; jb < CJ / 4; ++jb) {
      float4 wb = u4[tid + jb + 1];
      float4 k4 = *(const float4*)&Ks[CJ - 4 - (jb << 2)];
      acc0 += k4.w * wa.x + k4.z * wa.y + k4.y * wa.z + k4.x * wa.w;
      acc1 += k4.w * wa.y + k4.z * wa.z + k4.y * wa.w + k4.x * wb.x;
      acc2 += k4.w * wa.z + k4.z * wa.w + k4.y * wb.x + k4.x * wb.y;
      acc3 += k4.w * wa.w + k4.z * wb.x + k4.y * wb.y + k4.x * wb.z;
      wa = wb;
    }
  }
  int t = t0 + (tid << 2);
  atomicAdd(&y[t + 0], acc0);
  atomicAdd(&y[t + 1], acc1);
  atomicAdd(&y[t + 2], acc2);
  atomicAdd(&y[t + 3], acc3);
}

// ---------------- host ----------------

extern "C" void kernel_launch(void* const* d_in, const int* in_sizes, int n_in,
                              void* d_out, int out_size, void* d_ws, size_t ws_size,
                              hipStream_t stream) {
  const float* u  = (const float*)d_in[0];
  const float* A  = (const float*)d_in[1];
  const float* B  = (const float*)d_in[2];
  const float* Cm = (const float*)d_in[3];
  const float* ls = (const float*)d_in[4];
  float* y  = (float*)d_out;
  float* ws = (float*)d_ws;

  const int N = N_DIM;
  const size_t NN = (size_t)N * N;
  const size_t KR = (size_t)128 * N;
  float* b0 = ws;                     // E -> S
  float* b1 = b0 + NN;                // E2
  float* b2 = b1 + NN;                // S1
  float* Kv = b2 + NN;                // 128*128
  float* P  = Kv + L_SEQ;             // KS partial planes
  ushort_t* setA = (ushort_t*)(P + (size_t)KS * NN);
  ushort_t* setB = setA + 4 * NN;
  ushort_t* setC = setB + 4 * NN;
  ushort_t* VTset = setC + 4 * NN;    // {H,M} each 128xN
  ushort_t* Wset = VTset + 2 * KR;

  hipMemsetAsync(Kv, 0, (size_t)L_SEQ * sizeof(float), stream);
  hipMemsetAsync(y,  0, (size_t)L_SEQ * sizeof(float), stream);

  dim3 g16(16, 16);
  dim3 gSq(16, 16, 4);      // squaring-only
  dim3 gFull(16, 16, 5);    // squaring + skinny layer
  dim3 gSkF(16, 4);         // skinny-only

  // E = (step/2)*A ; 4-plane splits -> setA
  k_scalesplit<<<g16, 256, 0, stream>>>(A, ls, b0, setA);
  // E2 = E*E : f32 -> b1, T-splits -> setB
  gemm4f<<<gSq, 256, 0, stream>>>(setA, setA + 2 * NN, P, nullptr, nullptr, 0, 1);
  k_splitred<<<g16, 256, 0, stream>>>(P, nullptr, b1, setB, FW_F32 | FW_TSPLIT);
  // S1 = E + E2 : f32 -> b2, row-splits -> setA
  k_addsplit<<<NN / 1024, 256, 0, stream>>>(b0, b1, b2, setA);
  // S = S1*E2 + S1 : f32 S -> b0; Ab = 2S+I planes -> setC
  gemm4f<<<gSq, 256, 0, stream>>>(setA, setB + 2 * NN, P, nullptr, nullptr, 0, 1);
  k_splitred<<<g16, 256, 0, stream>>>(P, b2, b0, setC,
                                      FW_F32 | FW_ADDD | FW_MKAB | FW_SPLIT | FW_TSPLIT);
  // VT row0 = split(Bb); W row0 = split(C)
  k_bb<<<256, 256, 0, stream>>>(VTset, b0, B, ls);
  k_initW<<<4, 256, 0, stream>>>(Wset, Cm);

  // 13 fused steps: squaring partials + skinny Krylov, then splitred.
  ushort_t* cur = setC;
  ushort_t* oth = setA;
  for (int e = 0; e < 13; ++e) {
    int right = (e < 7);
    int s = 1 << (right ? e : (e - 7));
    gemm4f<<<gFull, 256, 0, stream>>>(cur, cur + 2 * NN, P,
                                      right ? cur : cur + 2 * NN,
                                      right ? VTset : Wset, s, 1);
    int fl = (e == 12) ? FW_TSPLIT : (FW_SPLIT | FW_TSPLIT);
    k_splitred<<<g16, 256, 0, stream>>>(P, nullptr, nullptr, oth, fl);
    ushort_t* tmp = cur; cur = oth; oth = tmp;
  }
  // final skinny-only: W rows 64->128 with Ab^8192
  gemm4f<<<gSkF, 256, 0, stream>>>(cur, cur + 2 * NN, P, cur + 2 * NN, Wset, 64, 0);
  // K = W . V
  k_combine<<<dim3(8, 2, 4), 256, 0, stream>>>(Wset, VTset, Kv);
  // y = causal conv(K, u)
  conv_k<<<g16, 256, 0, stream>>>(Kv, u, y);
}

// Round 7
// 538.172 us; speedup vs baseline: 4.5467x; 1.1696x over previous
//
#include <hip/hip_runtime.h>
#include <hip/hip_bf16.h>
#include <math.h>

#define N_DIM 1024
#define L_SEQ 16384
#define KS 4
#define SPSTR 65536  // 64*1024 skinny partial plane stride

typedef unsigned short ushort_t;
typedef __bf16 bf16x8 __attribute__((ext_vector_type(8)));
typedef float f32x4 __attribute__((ext_vector_type(4)));

#define FW_F32 1
#define FW_SPLIT 2
#define FW_TSPLIT 4
#define FW_ADDD 8
#define FW_MKAB 16

#define AS1 __attribute__((address_space(1)))
#define AS3 __attribute__((address_space(3)))

__device__ __forceinline__ void split2(float v, ushort_t& h, ushort_t& m) {
  union { __bf16 b; ushort_t u; } c;
  __bf16 bh = (__bf16)v;
  float fh = (float)bh;
  c.b = bh; h = c.u;
  c.b = (__bf16)(v - fh); m = c.u;
}

// ---------------- fused scale + 4-plane split: E = h*A -------------------
__global__ __launch_bounds__(256) void k_scalesplit(const float* __restrict__ A,
    const float* __restrict__ ls, float* __restrict__ E,
    ushort_t* __restrict__ set) {
  const size_t NN = (size_t)N_DIM * N_DIM;
  float hs = 0.5f * expf(ls[0]);
  int t = threadIdx.x;
  int r0 = blockIdx.x * 64 + ((t >> 4) << 2);
  int c0 = blockIdx.y * 64 + ((t & 15) << 2);
  float v[4][4];
#pragma unroll
  for (int i = 0; i < 4; ++i) {
    float4 f = *(const float4*)&A[(size_t)(r0 + i) * N_DIM + c0];
    v[i][0] = hs * f.x; v[i][1] = hs * f.y; v[i][2] = hs * f.z; v[i][3] = hs * f.w;
    *(float4*)&E[(size_t)(r0 + i) * N_DIM + c0] =
        make_float4(v[i][0], v[i][1], v[i][2], v[i][3]);
  }
  ushort_t h[4][4], m[4][4];
#pragma unroll
  for (int i = 0; i < 4; ++i)
#pragma unroll
    for (int j = 0; j < 4; ++j) split2(v[i][j], h[i][j], m[i][j]);
#pragma unroll
  for (int i = 0; i < 4; ++i) {
    size_t o = (size_t)(r0 + i) * N_DIM + c0;
    *(ushort4*)&set[o] = make_ushort4(h[i][0], h[i][1], h[i][2], h[i][3]);
    *(ushort4*)&set[NN + o] = make_ushort4(m[i][0], m[i][1], m[i][2], m[i][3]);
  }
#pragma unroll
  for (int j = 0; j < 4; ++j) {
    size_t o = (size_t)(c0 + j) * N_DIM + r0;
    *(ushort4*)&set[2 * NN + o] = make_ushort4(h[0][j], h[1][j], h[2][j], h[3][j]);
    *(ushort4*)&set[3 * NN + o] = make_ushort4(m[0][j], m[1][j], m[2][j], m[3][j]);
  }
}

// Cf = X + Y ; row-splits -> set{H,M}
__global__ __launch_bounds__(256) void k_addsplit(const float* __restrict__ X,
    const float* __restrict__ Y, float* __restrict__ Cf,
    ushort_t* __restrict__ set) {
  const size_t NN = (size_t)N_DIM * N_DIM;
  int i = (blockIdx.x * 256 + threadIdx.x) * 4;
  float4 a = *(const float4*)&X[i];
  float4 b = *(const float4*)&Y[i];
  float v[4] = {a.x + b.x, a.y + b.y, a.z + b.z, a.w + b.w};
  *(float4*)&Cf[i] = make_float4(v[0], v[1], v[2], v[3]);
  ushort_t h[4], m[4];
#pragma unroll
  for (int k = 0; k < 4; ++k) split2(v[k], h[k], m[k]);
  *(ushort4*)&set[i] = make_ushort4(h[0], h[1], h[2], h[3]);
  *(ushort4*)&set[NN + i] = make_ushort4(m[0], m[1], m[2], m[3]);
}

// blocks 0..255: VT row0 = split(step*(B + S@B)); blocks 256..259: W row0 = split(C)
__global__ __launch_bounds__(256) void k_bbinit(ushort_t* __restrict__ VTset,
    ushort_t* __restrict__ Wset, const float* __restrict__ S,
    const float* __restrict__ B, const float* __restrict__ Cm,
    const float* __restrict__ ls) {
  const size_t KR = (size_t)128 * N_DIM;
  int bx = blockIdx.x;
  if (bx >= 256) {
    int i = (bx - 256) * 256 + threadIdx.x;
    ushort_t h, m; split2(Cm[i], h, m);
    Wset[i] = h; Wset[KR + i] = m;
    return;
  }
  int row = bx * 4 + (threadIdx.x >> 6);
  int lane = threadIdx.x & 63;
  const float* Sr = S + (size_t)row * N_DIM;
  float sum = 0.f;
  for (int k = lane; k < N_DIM; k += 64) sum += Sr[k] * B[k];
  for (int off = 32; off; off >>= 1) sum += __shfl_down(sum, off);
  if (lane == 0) {
    float step = expf(ls[0]);
    float bb = step * (B[row] + sum);
    ushort_t h, m; split2(bb, h, m);
    VTset[row] = h; VTset[KR + row] = m;
  }
}

// ------- reduce KS partials (+D), optional mkAb, fp32/splits; y>=16: skinny reduce
__global__ __launch_bounds__(256) void k_splitred(
    const float* __restrict__ P,
    const float* __restrict__ D, float* __restrict__ Cf,
    ushort_t* __restrict__ set, int flags,
    const float* __restrict__ SP, ushort_t* __restrict__ Ka,
    int s, int ybase) {
  const size_t NN = (size_t)N_DIM * N_DIM;
  const size_t KR = (size_t)128 * N_DIM;
  int t = threadIdx.x;
  int ey = blockIdx.y + ybase;
  if (ey >= 16) {
    // skinny reduce: Ka rows [s,2s) over col-tile blockIdx.x
    int ct = blockIdx.x;
    for (int r0 = 0; r0 < s; r0 += 4) {
      int r = r0 + (t >> 6);
      int col = ct * 64 + (t & 63);
      if (r < s) {
        int o = r * 1024 + col;
        float v = SP[o] + SP[SPSTR + o] + SP[2 * SPSTR + o] + SP[3 * SPSTR + o];
        ushort_t h, m; split2(v, h, m);
        Ka[(size_t)(s + r) * N_DIM + col] = h;
        Ka[KR + (size_t)(s + r) * N_DIM + col] = m;
      }
    }
    return;
  }
  int r0 = blockIdx.x * 64 + ((t >> 4) << 2);
  int c0 = ey * 64 + ((t & 15) << 2);
  float v[4][4];
#pragma unroll
  for (int i = 0; i < 4; ++i) {
    float4 f = *(const float4*)&P[(size_t)(r0 + i) * N_DIM + c0];
    v[i][0] = f.x; v[i][1] = f.y; v[i][2] = f.z; v[i][3] = f.w;
  }
#pragma unroll
  for (int p = 1; p < KS; ++p) {
#pragma unroll
    for (int i = 0; i < 4; ++i) {
      float4 f = *(const float4*)&P[p * NN + (size_t)(r0 + i) * N_DIM + c0];
      v[i][0] += f.x; v[i][1] += f.y; v[i][2] += f.z; v[i][3] += f.w;
    }
  }
  if (flags & FW_ADDD) {
#pragma unroll
    for (int i = 0; i < 4; ++i) {
      float4 f = *(const float4*)&D[(size_t)(r0 + i) * N_DIM + c0];
      v[i][0] += f.x; v[i][1] += f.y; v[i][2] += f.z; v[i][3] += f.w;
    }
  }
  if (flags & FW_F32) {
#pragma unroll
    for (int i = 0; i < 4; ++i)
      *(float4*)&Cf[(size_t)(r0 + i) * N_DIM + c0] =
          make_float4(v[i][0], v[i][1], v[i][2], v[i][3]);
  }
  if (flags & FW_MKAB) {
#pragma unroll
    for (int i = 0; i < 4; ++i)
#pragma unroll
      for (int j = 0; j < 4; ++j)
        v[i][j] = 2.0f * v[i][j] + ((r0 + i) == (c0 + j) ? 1.0f : 0.0f);
  }
  if (flags & (FW_SPLIT | FW_TSPLIT)) {
    ushort_t h[4][4], m[4][4];
#pragma unroll
    for (int i = 0; i < 4; ++i)
#pragma unroll
      for (int j = 0; j < 4; ++j) split2(v[i][j], h[i][j], m[i][j]);
    if (flags & FW_SPLIT) {
#pragma unroll
      for (int i = 0; i < 4; ++i) {
        size_t o = (size_t)(r0 + i) * N_DIM + c0;
        *(ushort4*)&set[o] = make_ushort4(h[i][0], h[i][1], h[i][2], h[i][3]);
        *(ushort4*)&set[NN + o] = make_ushort4(m[i][0], m[i][1], m[i][2], m[i][3]);
      }
    }
    if (flags & FW_TSPLIT) {
#pragma unroll
      for (int j = 0; j < 4; ++j) {
        size_t o = (size_t)(c0 + j) * N_DIM + r0;
        *(ushort4*)&set[2 * NN + o] = make_ushort4(h[0][j], h[1][j], h[2][j], h[3][j]);
        *(ushort4*)&set[3 * NN + o] = make_ushort4(m[0][j], m[1][j], m[2][j], m[3][j]);
      }
    }
  }
}

// ---------------- fused: split-K squaring + split-K skinny Krylov ----------
// sqOn: y<16 -> squaring 64x64 tile, kChunk=256 -> P[z].
//       y>=16 -> skinny tile id=(y-16)*16+x, kChunk=256 -> SP[z].
// !sqOn: all blocks skinny, id = y*16+x.
__global__ __launch_bounds__(256) void gemm4f(
    const ushort_t* __restrict__ Qa, const ushort_t* __restrict__ Qbt,
    float* __restrict__ P, const ushort_t* __restrict__ SkB,
    const ushort_t* __restrict__ Ka, float* __restrict__ SP,
    int s, int sqOn) {
  const size_t NN = (size_t)N_DIM * N_DIM;
  const size_t KR = (size_t)128 * N_DIM;
  __shared__ __align__(16) ushort_t lds[16384];
  int t = threadIdx.x;
  const int lane = t & 63, w = t >> 6;
  bool isSk = (!sqOn) || ((int)blockIdx.y >= 16);

  if (!isSk) {
    int m0 = blockIdx.x * 64, n0 = blockIdx.y * 64;
    int kz = blockIdx.z;
    int r = t & 63, kc = t >> 6;
    const ushort_t* gA[2] = {Qa, Qa + NN};
    const ushort_t* gB[2] = {Qbt, Qbt + NN};
    size_t aoff = (size_t)(m0 + r) * N_DIM + kc * 8 + (size_t)kz * 256;
    size_t boff = (size_t)(n0 + r) * N_DIM + kc * 8 + (size_t)kz * 256;

    auto stage = [&](int buf, int k0) {
      ushort_t* dst = lds + buf * 8192;
#pragma unroll
      for (int L = 0; L < 2; ++L) {
        __builtin_amdgcn_global_load_lds(
            (const AS1 void*)(gA[L] + aoff + k0),
            (AS3 void*)(dst + L * 2048 + t * 8), 16, 0, 0);
        __builtin_amdgcn_global_load_lds(
            (const AS1 void*)(gB[L] + boff + k0),
            (AS3 void*)(dst + (2 + L) * 2048 + t * 8), 16, 0, 0);
      }
    };

    f32x4 acc[2][2];
#pragma unroll
    for (int i = 0; i < 2; ++i)
#pragma unroll
      for (int j = 0; j < 2; ++j) acc[i][j] = (f32x4){0.f, 0.f, 0.f, 0.f};

    const int wm = (w >> 1) * 32, wn = (w & 1) * 32;
    const int lrow = lane & 15, kg = lane >> 4;
    const int aIdx0 = kg * 512 + (wm + lrow) * 8;
    const int bIdx0 = 2 * 2048 + kg * 512 + (wn + lrow) * 8;

    stage(0, 0);
    __syncthreads();
    for (int ks = 0; ks < 8; ++ks) {
      int cur = ks & 1;
      if (ks < 7) stage(cur ^ 1, (ks + 1) * 32);
      const ushort_t* buf = lds + cur * 8192;
      bf16x8 a[2][2], b[2][2];
#pragma unroll
      for (int L = 0; L < 2; ++L) {
#pragma unroll
        for (int mi = 0; mi < 2; ++mi)
          a[L][mi] = *(const bf16x8*)&buf[L * 2048 + aIdx0 + mi * 128];
#pragma unroll
        for (int ni = 0; ni < 2; ++ni)
          b[L][ni] = *(const bf16x8*)&buf[bIdx0 + L * 2048 + ni * 128];
      }
#pragma unroll
      for (int mi = 0; mi < 2; ++mi)
#pragma unroll
        for (int ni = 0; ni < 2; ++ni) {
          f32x4 c = acc[mi][ni];
          c = __builtin_amdgcn_mfma_f32_16x16x32_bf16(a[0][mi], b[0][ni], c, 0, 0, 0);
          c = __builtin_amdgcn_mfma_f32_16x16x32_bf16(a[0][mi], b[1][ni], c, 0, 0, 0);
          c = __builtin_amdgcn_mfma_f32_16x16x32_bf16(a[1][mi], b[0][ni], c, 0, 0, 0);
          c = __builtin_amdgcn_mfma_f32_16x16x32_bf16(a[1][mi], b[1][ni], c, 0, 0, 0);
          acc[mi][ni] = c;
        }
      __syncthreads();
    }

    float* Pk = P + (size_t)kz * NN;
#pragma unroll
    for (int mi = 0; mi < 2; ++mi)
#pragma unroll
      for (int ni = 0; ni < 2; ++ni) {
        int rowb = m0 + wm + mi * 16 + kg * 4;
        int col = n0 + wn + ni * 16 + lrow;
#pragma unroll
        for (int j = 0; j < 4; ++j)
          Pk[(size_t)(rowb + j) * N_DIM + col] = acc[mi][ni][j];
      }
    return;
  }

  // ---- skinny Krylov, split-K ----
  int id = sqOn ? ((int)blockIdx.y - 16) * 16 + (int)blockIdx.x
                : (int)blockIdx.y * 16 + (int)blockIdx.x;
  int kz = blockIdx.z;
  int rt = id >> 4, ct = id & 15;
  if (rt >= ((s + 15) >> 4)) return;
  const ushort_t* Ah = Ka;
  const ushort_t* Amm = Ka + KR;
  const ushort_t* Bh = SkB;
  const ushort_t* Bm = SkB + NN;
  const int lrow = lane & 15, kg = lane >> 4;
  int kBase = kz * 256;

  auto stageS = [&](int buf, int k0) {
    ushort_t* base = lds + buf * 5120;
    if (t < 128) {
      int lvl = t >> 6, rem = t & 63, kcc = rem >> 4, i = rem & 15;
      const ushort_t* src =
          (lvl ? Amm : Ah) + (size_t)(rt * 16 + i) * N_DIM + k0 + kcc * 8;
      __builtin_amdgcn_global_load_lds((const AS1 void*)src,
                                       (AS3 void*)(base + t * 8), 16, 0, 0);
    }
#pragma unroll
    for (int it2 = 0; it2 < 2; ++it2) {
      int t2 = t + it2 * 256;
      int lvl = t2 >> 8, rem = t2 & 255, kcc = rem >> 6, c = rem & 63;
      const ushort_t* src =
          (lvl ? Bm : Bh) + (size_t)(ct * 64 + c) * N_DIM + k0 + kcc * 8;
      __builtin_amdgcn_global_load_lds(
          (const AS1 void*)src, (AS3 void*)(base + 1024 + t2 * 8), 16, 0, 0);
    }
  };

  f32x4 acc = (f32x4){0.f, 0.f, 0.f, 0.f};
  const int aO = kg * 128 + lrow * 8;
  const int bO = 1024 + kg * 512 + (w * 16 + lrow) * 8;

  stageS(0, kBase);
  __syncthreads();
  for (int ks2 = 0; ks2 < 8; ++ks2) {
    int cur = ks2 & 1;
    if (ks2 < 7) stageS(cur ^ 1, kBase + (ks2 + 1) * 32);
    const ushort_t* b = lds + cur * 5120;
    bf16x8 a0 = *(const bf16x8*)&b[aO];
    bf16x8 a1 = *(const bf16x8*)&b[aO + 512];
    bf16x8 b0v = *(const bf16x8*)&b[bO];
    bf16x8 b1v = *(const bf16x8*)&b[bO + 2048];
    acc = __builtin_amdgcn_mfma_f32_16x16x32_bf16(a0, b0v, acc, 0, 0, 0);
    acc = __builtin_amdgcn_mfma_f32_16x16x32_bf16(a0, b1v, acc, 0, 0, 0);
    acc = __builtin_amdgcn_mfma_f32_16x16x32_bf16(a1, b0v, acc, 0, 0, 0);
    acc = __builtin_amdgcn_mfma_f32_16x16x32_bf16(a1, b1v, acc, 0, 0, 0);
    __syncthreads();
  }

  float* sp = SP + (size_t)kz * SPSTR;
  int col = ct * 64 + w * 16 + lrow;
#pragma unroll
  for (int j = 0; j < 4; ++j) {
    int ir = rt * 16 + kg * 4 + j;
    if (ir < s) sp[ir * 1024 + col] = acc[j];
  }
}

// ---------------- combine: Kv[q*128+r] = W[q,:] . V[:,r] -------------------
__global__ __launch_bounds__(256) void k_combine(
    const ushort_t* __restrict__ Wset, const ushort_t* __restrict__ Vset,
    float* __restrict__ Kv) {
  const size_t KR = (size_t)128 * N_DIM;
  __shared__ __align__(16) ushort_t lds[2][5120];
  int t = threadIdx.x;
  int rt = blockIdx.x, ct = blockIdx.y, kz = blockIdx.z;
  int kBase = kz * 256;
  const ushort_t* Ah = Wset;
  const ushort_t* Amm = Wset + KR;
  const ushort_t* Bh = Vset;
  const ushort_t* Bm = Vset + KR;
  ushort_t* L = &lds[0][0];
  const int lane = t & 63, w = t >> 6;
  const int lrow = lane & 15, kg = lane >> 4;

  auto stageS = [&](int buf, int k0) {
    ushort_t* base = L + buf * 5120;
    if (t < 128) {
      int lvl = t >> 6, rem = t & 63, kcc = rem >> 4, i = rem & 15;
      const ushort_t* src =
          (lvl ? Amm : Ah) + (size_t)(rt * 16 + i) * N_DIM + k0 + kcc * 8;
      __builtin_amdgcn_global_load_lds((const AS1 void*)src,
                                       (AS3 void*)(base + t * 8), 16, 0, 0);
    }
#pragma unroll
    for (int it = 0; it < 2; ++it) {
      int t2 = t + it * 256;
      int lvl = t2 >> 8, rem = t2 & 255, kcc = rem >> 6, c = rem & 63;
      const ushort_t* src =
          (lvl ? Bm : Bh) + (size_t)(ct * 64 + c) * N_DIM + k0 + kcc * 8;
      __builtin_amdgcn_global_load_lds(
          (const AS1 void*)src, (AS3 void*)(base + 1024 + t2 * 8), 16, 0, 0);
    }
  };

  f32x4 acc = (f32x4){0.f, 0.f, 0.f, 0.f};
  const int aO = kg * 128 + lrow * 8;
  const int bO = 1024 + kg * 512 + (w * 16 + lrow) * 8;

  stageS(0, kBase);
  __syncthreads();
  for (int ks = 0; ks < 8; ++ks) {
    int cur = ks & 1;
    if (ks < 7) stageS(cur ^ 1, kBase + (ks + 1) * 32);
    const ushort_t* b = L + cur * 5120;
    bf16x8 a0 = *(const bf16x8*)&b[aO];
    bf16x8 a1 = *(const bf16x8*)&b[aO + 512];
    bf16x8 b0v = *(const bf16x8*)&b[bO];
    bf16x8 b1v = *(const bf16x8*)&b[bO + 2048];
    acc = __builtin_amdgcn_mfma_f32_16x16x32_bf16(a0, b0v, acc, 0, 0, 0);
    acc = __builtin_amdgcn_mfma_f32_16x16x32_bf16(a0, b1v, acc, 0, 0, 0);
    acc = __builtin_amdgcn_mfma_f32_16x16x32_bf16(a1, b0v, acc, 0, 0, 0);
    acc = __builtin_amdgcn_mfma_f32_16x16x32_bf16(a1, b1v, acc, 0, 0, 0);
    __syncthreads();
  }

  int rcol = ct * 64 + w * 16 + lrow;
#pragma unroll
  for (int j = 0; j < 4; ++j) {
    int q = rt * 16 + kg * 4 + j;
    atomicAdd(&Kv[q * 128 + rcol], acc[j]);
  }
}

// ---------------- causal convolution --------------------------------------
__global__ __launch_bounds__(256) void conv_k(const float* __restrict__ Kv,
    const float* __restrict__ u, float* __restrict__ y) {
  const int CT = 1024, CJ = 256, LCH = 1024;
  int t0 = blockIdx.x * CT;
  int l0 = blockIdx.y * LCH;
  if (l0 > t0 + CT - 1) return;
  __shared__ __align__(16) float Ks[CJ];
  __shared__ __align__(16) float us[CT + CJ + 8];
  int tid = threadIdx.x;
  float acc0 = 0.f, acc1 = 0.f, acc2 = 0.f, acc3 = 0.f;
  int ltEnd = l0 + LCH; if (ltEnd > t0 + CT) ltEnd = t0 + CT;
  for (int lt = l0; lt < ltEnd; lt += CJ) {
    __syncthreads();
    Ks[tid] = Kv[lt + tid];
    int ub = t0 - lt - (CJ - 1);
    for (int s = tid; s < CT + CJ + 4; s += 256) {
      int g = ub + s;
      us[s] = (g >= 0 && g < L_SEQ) ? u[g] : 0.f;
    }
    __syncthreads();
    const float4* u4 = (const float4*)us;
    float4 wa = u4[tid];
#pragma unroll 4
    for (int jb = 0; jb < CJ / 4; ++jb) {
      float4 wb = u4[tid + jb + 1];
      float4 k4 = *(const float4*)&Ks[CJ - 4 - (jb << 2)];
      acc0 += k4.w * wa.x + k4.z * wa.y + k4.y * wa.z + k4.x * wa.w;
      acc1 += k4.w * wa.y + k4.z * wa.z + k4.y * wa.w + k4.x * wb.x;
      acc2 += k4.w * wa.z + k4.z * wa.w + k4.y * wb.x + k4.x * wb.y;
      acc3 += k4.w * wa.w + k4.z * wb.x + k4.y * wb.y + k4.x * wb.z;
      wa = wb;
    }
  }
  int t = t0 + (tid << 2);
  atomicAdd(&y[t + 0], acc0);
  atomicAdd(&y[t + 1], acc1);
  atomicAdd(&y[t + 2], acc2);
  atomicAdd(&y[t + 3], acc3);
}

// ---------------- host ----------------

extern "C" void kernel_launch(void* const* d_in, const int* in_sizes, int n_in,
                              void* d_out, int out_size, void* d_ws, size_t ws_size,
                              hipStream_t stream) {
  const float* u  = (const float*)d_in[0];
  const float* A  = (const float*)d_in[1];
  const float* B  = (const float*)d_in[2];
  const float* Cm = (const float*)d_in[3];
  const float* ls = (const float*)d_in[4];
  float* y  = (float*)d_out;
  float* ws = (float*)d_ws;

  const int N = N_DIM;
  const size_t NN = (size_t)N * N;
  const size_t KR = (size_t)128 * N;
  float* b0 = ws;                     // E -> S
  float* b1 = b0 + NN;                // E2
  float* b2 = b1 + NN;                // S1
  float* Kv = b2 + NN;                // 128*128
  float* P  = Kv + L_SEQ;             // KS partial planes
  float* SP = P + (size_t)KS * NN;    // KS skinny partial planes (64x1024)
  ushort_t* setA = (ushort_t*)(SP + (size_t)KS * SPSTR);
  ushort_t* setB = setA + 4 * NN;
  ushort_t* setC = setB + 4 * NN;
  ushort_t* VTset = setC + 4 * NN;    // {H,M} each 128xN
  ushort_t* Wset = VTset + 2 * KR;

  hipMemsetAsync(Kv, 0, (size_t)L_SEQ * sizeof(float), stream);
  hipMemsetAsync(y,  0, (size_t)L_SEQ * sizeof(float), stream);

  dim3 g16(16, 16);
  dim3 gSq(16, 16, KS);     // squaring-only
  dim3 gFull(16, 20, KS);   // squaring + skinny split-K layers
  dim3 gRed(16, 17);        // reduce + skinny-reduce
  dim3 gSkF(16, 4, KS);     // final skinny-only
  dim3 gSkR(16, 1);         // final skinny reduce

  // E = (step/2)*A ; 4-plane splits -> setA
  k_scalesplit<<<g16, 256, 0, stream>>>(A, ls, b0, setA);
  // E2 = E*E : f32 -> b1, T-splits -> setB
  gemm4f<<<gSq, 256, 0, stream>>>(setA, setA + 2 * NN, P, nullptr, nullptr,
                                  SP, 0, 1);
  k_splitred<<<g16, 256, 0, stream>>>(P, nullptr, b1, setB, FW_F32 | FW_TSPLIT,
                                      nullptr, nullptr, 0, 0);
  // S1 = E + E2 : f32 -> b2, row-splits -> setA
  k_addsplit<<<NN / 1024, 256, 0, stream>>>(b0, b1, b2, setA);
  // S = S1*E2 + S1 : f32 S -> b0; Ab = 2S+I planes -> setC
  gemm4f<<<gSq, 256, 0, stream>>>(setA, setB + 2 * NN, P, nullptr, nullptr,
                                  SP, 0, 1);
  k_splitred<<<g16, 256, 0, stream>>>(P, b2, b0, setC,
                                      FW_F32 | FW_ADDD | FW_MKAB | FW_SPLIT | FW_TSPLIT,
                                      nullptr, nullptr, 0, 0);
  // VT row0 = split(Bb); W row0 = split(C)
  k_bbinit<<<260, 256, 0, stream>>>(VTset, Wset, b0, B, Cm, ls);

  // 13 fused steps: squaring + skinny split-K, then fused reduce.
  ushort_t* cur = setC;
  ushort_t* oth = setA;
  for (int e = 0; e < 13; ++e) {
    int right = (e < 7);
    int s = 1 << (right ? e : (e - 7));
    ushort_t* Ka = right ? VTset : Wset;
    const ushort_t* SkB = right ? cur : cur + 2 * NN;
    gemm4f<<<gFull, 256, 0, stream>>>(cur, cur + 2 * NN, P, SkB, Ka, SP, s, 1);
    int fl = (e == 12) ? FW_TSPLIT : (FW_SPLIT | FW_TSPLIT);
    k_splitred<<<gRed, 256, 0, stream>>>(P, nullptr, nullptr, oth, fl,
                                         SP, Ka, s, 0);
    ushort_t* tmp = cur; cur = oth; oth = tmp;
  }
  // final skinny-only: W rows 64->128 with Ab^8192 (T-splits of cur)
  gemm4f<<<gSkF, 256, 0, stream>>>(cur, cur + 2 * NN, P, cur + 2 * NN, Wset,
                                   SP, 64, 0);
  k_splitred<<<gSkR, 256, 0, stream>>>(P, nullptr, nullptr, nullptr, 0,
                                       SP, Wset, 64, 16);
  // K = W . V
  k_combine<<<dim3(8, 2, KS), 256, 0, stream>>>(Wset, VTset, Kv);
  // y = causal conv(K, u)
  conv_k<<<g16, 256, 0, stream>>>(Kv, u, y);
}

// Round 8
// 498.437 us; speedup vs baseline: 4.9092x; 1.0797x over previous
//
#include <hip/hip_runtime.h>
#include <hip/hip_bf16.h>
#include <math.h>

#define N_DIM 1024
#define L_SEQ 16384
#define KS 4
#define SPSTR 65536  // 64*1024 skinny partial plane stride

typedef unsigned short ushort_t;
typedef __bf16 bf16x8 __attribute__((ext_vector_type(8)));
typedef float f32x4 __attribute__((ext_vector_type(4)));

#define FW_F32 1
#define FW_SPLIT 2
#define FW_TSPLIT 4
#define FW_ADDD 8
#define FW_MKAB 16

#define AS1 __attribute__((address_space(1)))
#define AS3 __attribute__((address_space(3)))

__device__ __forceinline__ void split2(float v, ushort_t& h, ushort_t& m) {
  union { __bf16 b; ushort_t u; } c;
  __bf16 bh = (__bf16)v;
  float fh = (float)bh;
  c.b = bh; h = c.u;
  c.b = (__bf16)(v - fh); m = c.u;
}

// ---------------- fused scale + 4-plane split: E = h*A -------------------
__global__ __launch_bounds__(256) void k_scalesplit(const float* __restrict__ A,
    const float* __restrict__ ls, float* __restrict__ E,
    ushort_t* __restrict__ set) {
  const size_t NN = (size_t)N_DIM * N_DIM;
  float hs = 0.5f * expf(ls[0]);
  int t = threadIdx.x;
  int r0 = blockIdx.x * 64 + ((t >> 4) << 2);
  int c0 = blockIdx.y * 64 + ((t & 15) << 2);
  float v[4][4];
#pragma unroll
  for (int i = 0; i < 4; ++i) {
    float4 f = *(const float4*)&A[(size_t)(r0 + i) * N_DIM + c0];
    v[i][0] = hs * f.x; v[i][1] = hs * f.y; v[i][2] = hs * f.z; v[i][3] = hs * f.w;
    *(float4*)&E[(size_t)(r0 + i) * N_DIM + c0] =
        make_float4(v[i][0], v[i][1], v[i][2], v[i][3]);
  }
  ushort_t h[4][4], m[4][4];
#pragma unroll
  for (int i = 0; i < 4; ++i)
#pragma unroll
    for (int j = 0; j < 4; ++j) split2(v[i][j], h[i][j], m[i][j]);
#pragma unroll
  for (int i = 0; i < 4; ++i) {
    size_t o = (size_t)(r0 + i) * N_DIM + c0;
    *(ushort4*)&set[o] = make_ushort4(h[i][0], h[i][1], h[i][2], h[i][3]);
    *(ushort4*)&set[NN + o] = make_ushort4(m[i][0], m[i][1], m[i][2], m[i][3]);
  }
#pragma unroll
  for (int j = 0; j < 4; ++j) {
    size_t o = (size_t)(c0 + j) * N_DIM + r0;
    *(ushort4*)&set[2 * NN + o] = make_ushort4(h[0][j], h[1][j], h[2][j], h[3][j]);
    *(ushort4*)&set[3 * NN + o] = make_ushort4(m[0][j], m[1][j], m[2][j], m[3][j]);
  }
}

// Cf = X + Y ; row-splits -> set{H,M}
__global__ __launch_bounds__(256) void k_addsplit(const float* __restrict__ X,
    const float* __restrict__ Y, float* __restrict__ Cf,
    ushort_t* __restrict__ set) {
  const size_t NN = (size_t)N_DIM * N_DIM;
  int i = (blockIdx.x * 256 + threadIdx.x) * 4;
  float4 a = *(const float4*)&X[i];
  float4 b = *(const float4*)&Y[i];
  float v[4] = {a.x + b.x, a.y + b.y, a.z + b.z, a.w + b.w};
  *(float4*)&Cf[i] = make_float4(v[0], v[1], v[2], v[3]);
  ushort_t h[4], m[4];
#pragma unroll
  for (int k = 0; k < 4; ++k) split2(v[k], h[k], m[k]);
  *(ushort4*)&set[i] = make_ushort4(h[0], h[1], h[2], h[3]);
  *(ushort4*)&set[NN + i] = make_ushort4(m[0], m[1], m[2], m[3]);
}

// blocks 0..255: VT row0 = split(step*(B + S@B)); blocks 256..259: W row0 = split(C)
__global__ __launch_bounds__(256) void k_bbinit(ushort_t* __restrict__ VTset,
    ushort_t* __restrict__ Wset, const float* __restrict__ S,
    const float* __restrict__ B, const float* __restrict__ Cm,
    const float* __restrict__ ls) {
  const size_t KR = (size_t)128 * N_DIM;
  int bx = blockIdx.x;
  if (bx >= 256) {
    int i = (bx - 256) * 256 + threadIdx.x;
    ushort_t h, m; split2(Cm[i], h, m);
    Wset[i] = h; Wset[KR + i] = m;
    return;
  }
  int row = bx * 4 + (threadIdx.x >> 6);
  int lane = threadIdx.x & 63;
  const float* Sr = S + (size_t)row * N_DIM;
  float sum = 0.f;
  for (int k = lane; k < N_DIM; k += 64) sum += Sr[k] * B[k];
  for (int off = 32; off; off >>= 1) sum += __shfl_down(sum, off);
  if (lane == 0) {
    float step = expf(ls[0]);
    float bb = step * (B[row] + sum);
    ushort_t h, m; split2(bb, h, m);
    VTset[row] = h; VTset[KR + row] = m;
  }
}

// ------- reduce KS partials (+D), optional mkAb, fp32/splits; y>=16: skinny reduce
__global__ __launch_bounds__(256) void k_splitred(
    const float* __restrict__ P,
    const float* __restrict__ D, float* __restrict__ Cf,
    ushort_t* __restrict__ set, int flags,
    const float* __restrict__ SP, ushort_t* __restrict__ Ka,
    int s, int ybase) {
  const size_t NN = (size_t)N_DIM * N_DIM;
  const size_t KR = (size_t)128 * N_DIM;
  int t = threadIdx.x;
  int ey = blockIdx.y + ybase;
  if (ey >= 16) {
    int ct = blockIdx.x;
    for (int r0 = 0; r0 < s; r0 += 4) {
      int r = r0 + (t >> 6);
      int col = ct * 64 + (t & 63);
      if (r < s) {
        int o = r * 1024 + col;
        float v = SP[o] + SP[SPSTR + o] + SP[2 * SPSTR + o] + SP[3 * SPSTR + o];
        ushort_t h, m; split2(v, h, m);
        Ka[(size_t)(s + r) * N_DIM + col] = h;
        Ka[KR + (size_t)(s + r) * N_DIM + col] = m;
      }
    }
    return;
  }
  int r0 = blockIdx.x * 64 + ((t >> 4) << 2);
  int c0 = ey * 64 + ((t & 15) << 2);
  float v[4][4];
#pragma unroll
  for (int i = 0; i < 4; ++i) {
    float4 f = *(const float4*)&P[(size_t)(r0 + i) * N_DIM + c0];
    v[i][0] = f.x; v[i][1] = f.y; v[i][2] = f.z; v[i][3] = f.w;
  }
#pragma unroll
  for (int p = 1; p < KS; ++p) {
#pragma unroll
    for (int i = 0; i < 4; ++i) {
      float4 f = *(const float4*)&P[p * NN + (size_t)(r0 + i) * N_DIM + c0];
      v[i][0] += f.x; v[i][1] += f.y; v[i][2] += f.z; v[i][3] += f.w;
    }
  }
  if (flags & FW_ADDD) {
#pragma unroll
    for (int i = 0; i < 4; ++i) {
      float4 f = *(const float4*)&D[(size_t)(r0 + i) * N_DIM + c0];
      v[i][0] += f.x; v[i][1] += f.y; v[i][2] += f.z; v[i][3] += f.w;
    }
  }
  if (flags & FW_F32) {
#pragma unroll
    for (int i = 0; i < 4; ++i)
      *(float4*)&Cf[(size_t)(r0 + i) * N_DIM + c0] =
          make_float4(v[i][0], v[i][1], v[i][2], v[i][3]);
  }
  if (flags & FW_MKAB) {
#pragma unroll
    for (int i = 0; i < 4; ++i)
#pragma unroll
      for (int j = 0; j < 4; ++j)
        v[i][j] = 2.0f * v[i][j] + ((r0 + i) == (c0 + j) ? 1.0f : 0.0f);
  }
  if (flags & (FW_SPLIT | FW_TSPLIT)) {
    ushort_t h[4][4], m[4][4];
#pragma unroll
    for (int i = 0; i < 4; ++i)
#pragma unroll
      for (int j = 0; j < 4; ++j) split2(v[i][j], h[i][j], m[i][j]);
    if (flags & FW_SPLIT) {
#pragma unroll
      for (int i = 0; i < 4; ++i) {
        size_t o = (size_t)(r0 + i) * N_DIM + c0;
        *(ushort4*)&set[o] = make_ushort4(h[i][0], h[i][1], h[i][2], h[i][3]);
        *(ushort4*)&set[NN + o] = make_ushort4(m[i][0], m[i][1], m[i][2], m[i][3]);
      }
    }
    if (flags & FW_TSPLIT) {
#pragma unroll
      for (int j = 0; j < 4; ++j) {
        size_t o = (size_t)(c0 + j) * N_DIM + r0;
        *(ushort4*)&set[2 * NN + o] = make_ushort4(h[0][j], h[1][j], h[2][j], h[3][j]);
        *(ushort4*)&set[3 * NN + o] = make_ushort4(m[0][j], m[1][j], m[2][j], m[3][j]);
      }
    }
  }
}

// ---------------- fused: split-K squaring + split-K skinny Krylov ----------
// Counted-vmcnt double-buffer pipeline (T4): raw s_barrier + vmcnt(N), loads
// stay in flight across the barrier; compute(k) waits only stage(k)'s loads.
__global__ __launch_bounds__(256) void gemm4f(
    const ushort_t* __restrict__ Qa, const ushort_t* __restrict__ Qbt,
    float* __restrict__ P, const ushort_t* __restrict__ SkB,
    const ushort_t* __restrict__ Ka, float* __restrict__ SP,
    int s, int sqOn) {
  const size_t NN = (size_t)N_DIM * N_DIM;
  const size_t KR = (size_t)128 * N_DIM;
  __shared__ __align__(16) ushort_t lds[16384];
  int t = threadIdx.x;
  const int lane = t & 63, w = t >> 6;
  bool isSk = (!sqOn) || ((int)blockIdx.y >= 16);

  if (!isSk) {
    int m0 = blockIdx.x * 64, n0 = blockIdx.y * 64;
    int kz = blockIdx.z;
    int r = t & 63, kc = t >> 6;
    const ushort_t* gA[2] = {Qa, Qa + NN};
    const ushort_t* gB[2] = {Qbt, Qbt + NN};
    size_t aoff = (size_t)(m0 + r) * N_DIM + kc * 8 + (size_t)kz * 256;
    size_t boff = (size_t)(n0 + r) * N_DIM + kc * 8 + (size_t)kz * 256;

    auto stage = [&](int buf, int k0) {  // 4 load instrs per wave
      ushort_t* dst = lds + buf * 8192;
#pragma unroll
      for (int L = 0; L < 2; ++L) {
        __builtin_amdgcn_global_load_lds(
            (const AS1 void*)(gA[L] + aoff + k0),
            (AS3 void*)(dst + L * 2048 + t * 8), 16, 0, 0);
        __builtin_amdgcn_global_load_lds(
            (const AS1 void*)(gB[L] + boff + k0),
            (AS3 void*)(dst + (2 + L) * 2048 + t * 8), 16, 0, 0);
      }
    };

    f32x4 acc[2][2];
#pragma unroll
    for (int i = 0; i < 2; ++i)
#pragma unroll
      for (int j = 0; j < 2; ++j) acc[i][j] = (f32x4){0.f, 0.f, 0.f, 0.f};

    const int wm = (w >> 1) * 32, wn = (w & 1) * 32;
    const int lrow = lane & 15, kg = lane >> 4;
    const int aIdx0 = kg * 512 + (wm + lrow) * 8;
    const int bIdx0 = 2 * 2048 + kg * 512 + (wn + lrow) * 8;

    stage(0, 0);
    asm volatile("s_waitcnt vmcnt(0)" ::: "memory");
    __builtin_amdgcn_s_barrier();
    for (int ks = 0; ks < 8; ++ks) {
      int cur = ks & 1;
      if (ks < 7) {
        stage(cur ^ 1, (ks + 1) * 32);
        asm volatile("s_waitcnt vmcnt(4)" ::: "memory");  // cur's 4 landed
      } else {
        asm volatile("s_waitcnt vmcnt(0)" ::: "memory");
      }
      __builtin_amdgcn_s_barrier();          // buf[cur] visible to all waves
      __builtin_amdgcn_sched_barrier(0);
      const ushort_t* buf = lds + cur * 8192;
      bf16x8 a[2][2], b[2][2];
#pragma unroll
      for (int L = 0; L < 2; ++L) {
#pragma unroll
        for (int mi = 0; mi < 2; ++mi)
          a[L][mi] = *(const bf16x8*)&buf[L * 2048 + aIdx0 + mi * 128];
#pragma unroll
        for (int ni = 0; ni < 2; ++ni)
          b[L][ni] = *(const bf16x8*)&buf[bIdx0 + L * 2048 + ni * 128];
      }
#pragma unroll
      for (int mi = 0; mi < 2; ++mi)
#pragma unroll
        for (int ni = 0; ni < 2; ++ni) {
          f32x4 c = acc[mi][ni];
          c = __builtin_amdgcn_mfma_f32_16x16x32_bf16(a[0][mi], b[0][ni], c, 0, 0, 0);
          c = __builtin_amdgcn_mfma_f32_16x16x32_bf16(a[0][mi], b[1][ni], c, 0, 0, 0);
          c = __builtin_amdgcn_mfma_f32_16x16x32_bf16(a[1][mi], b[0][ni], c, 0, 0, 0);
          c = __builtin_amdgcn_mfma_f32_16x16x32_bf16(a[1][mi], b[1][ni], c, 0, 0, 0);
          acc[mi][ni] = c;
        }
      if (ks < 7) __builtin_amdgcn_s_barrier();  // reads of buf[cur] done
    }

    float* Pk = P + (size_t)kz * NN;
#pragma unroll
    for (int mi = 0; mi < 2; ++mi)
#pragma unroll
      for (int ni = 0; ni < 2; ++ni) {
        int rowb = m0 + wm + mi * 16 + kg * 4;
        int col = n0 + wn + ni * 16 + lrow;
#pragma unroll
        for (int j = 0; j < 4; ++j)
          Pk[(size_t)(rowb + j) * N_DIM + col] = acc[mi][ni][j];
      }
    return;
  }

  // ---- skinny Krylov, split-K (waves 0-1: 3 loads/stage, waves 2-3: 2) ----
  int id = sqOn ? ((int)blockIdx.y - 16) * 16 + (int)blockIdx.x
                : (int)blockIdx.y * 16 + (int)blockIdx.x;
  int kz = blockIdx.z;
  int rt = id >> 4, ct = id & 15;
  if (rt >= ((s + 15) >> 4)) return;
  const ushort_t* Ah = Ka;
  const ushort_t* Amm = Ka + KR;
  const ushort_t* Bh = SkB;
  const ushort_t* Bm = SkB + NN;
  const int lrow = lane & 15, kg = lane >> 4;
  int kBase = kz * 256;

  auto stageS = [&](int buf, int k0) {
    ushort_t* base = lds + buf * 5120;
    if (t < 128) {
      int lvl = t >> 6, rem = t & 63, kcc = rem >> 4, i = rem & 15;
      const ushort_t* src =
          (lvl ? Amm : Ah) + (size_t)(rt * 16 + i) * N_DIM + k0 + kcc * 8;
      __builtin_amdgcn_global_load_lds((const AS1 void*)src,
                                       (AS3 void*)(base + t * 8), 16, 0, 0);
    }
#pragma unroll
    for (int it2 = 0; it2 < 2; ++it2) {
      int t2 = t + it2 * 256;
      int lvl = t2 >> 8, rem = t2 & 255, kcc = rem >> 6, c = rem & 63;
      const ushort_t* src =
          (lvl ? Bm : Bh) + (size_t)(ct * 64 + c) * N_DIM + k0 + kcc * 8;
      __builtin_amdgcn_global_load_lds(
          (const AS1 void*)src, (AS3 void*)(base + 1024 + t2 * 8), 16, 0, 0);
    }
  };

  f32x4 acc = (f32x4){0.f, 0.f, 0.f, 0.f};
  const int aO = kg * 128 + lrow * 8;
  const int bO = 1024 + kg * 512 + (w * 16 + lrow) * 8;

  stageS(0, kBase);
  asm volatile("s_waitcnt vmcnt(0)" ::: "memory");
  __builtin_amdgcn_s_barrier();
  for (int ks2 = 0; ks2 < 8; ++ks2) {
    int cur = ks2 & 1;
    if (ks2 < 7) {
      stageS(cur ^ 1, kBase + (ks2 + 1) * 32);
      if (w < 2) asm volatile("s_waitcnt vmcnt(3)" ::: "memory");
      else       asm volatile("s_waitcnt vmcnt(2)" ::: "memory");
    } else {
      asm volatile("s_waitcnt vmcnt(0)" ::: "memory");
    }
    __builtin_amdgcn_s_barrier();
    __builtin_amdgcn_sched_barrier(0);
    const ushort_t* b = lds + cur * 5120;
    bf16x8 a0 = *(const bf16x8*)&b[aO];
    bf16x8 a1 = *(const bf16x8*)&b[aO + 512];
    bf16x8 b0v = *(const bf16x8*)&b[bO];
    bf16x8 b1v = *(const bf16x8*)&b[bO + 2048];
    acc = __builtin_amdgcn_mfma_f32_16x16x32_bf16(a0, b0v, acc, 0, 0, 0);
    acc = __builtin_amdgcn_mfma_f32_16x16x32_bf16(a0, b1v, acc, 0, 0, 0);
    acc = __builtin_amdgcn_mfma_f32_16x16x32_bf16(a1, b0v, acc, 0, 0, 0);
    acc = __builtin_amdgcn_mfma_f32_16x16x32_bf16(a1, b1v, acc, 0, 0, 0);
    if (ks2 < 7) __builtin_amdgcn_s_barrier();
  }

  float* sp = SP + (size_t)kz * SPSTR;
  int col = ct * 64 + w * 16 + lrow;
#pragma unroll
  for (int j = 0; j < 4; ++j) {
    int ir = rt * 16 + kg * 4 + j;
    if (ir < s) sp[ir * 1024 + col] = acc[j];
  }
}

// ---------------- combine: Kv[q*128+r] = W[q,:] . V[:,r] -------------------
__global__ __launch_bounds__(256) void k_combine(
    const ushort_t* __restrict__ Wset, const ushort_t* __restrict__ Vset,
    float* __restrict__ Kv) {
  const size_t KR = (size_t)128 * N_DIM;
  __shared__ __align__(16) ushort_t lds[2][5120];
  int t = threadIdx.x;
  int rt = blockIdx.x, ct = blockIdx.y, kz = blockIdx.z;
  int kBase = kz * 256;
  const ushort_t* Ah = Wset;
  const ushort_t* Amm = Wset + KR;
  const ushort_t* Bh = Vset;
  const ushort_t* Bm = Vset + KR;
  ushort_t* L = &lds[0][0];
  const int lane = t & 63, w = t >> 6;
  const int lrow = lane & 15, kg = lane >> 4;

  auto stageS = [&](int buf, int k0) {
    ushort_t* base = L + buf * 5120;
    if (t < 128) {
      int lvl = t >> 6, rem = t & 63, kcc = rem >> 4, i = rem & 15;
      const ushort_t* src =
          (lvl ? Amm : Ah) + (size_t)(rt * 16 + i) * N_DIM + k0 + kcc * 8;
      __builtin_amdgcn_global_load_lds((const AS1 void*)src,
                                       (AS3 void*)(base + t * 8), 16, 0, 0);
    }
#pragma unroll
    for (int it = 0; it < 2; ++it) {
      int t2 = t + it * 256;
      int lvl = t2 >> 8, rem = t2 & 255, kcc = rem >> 6, c = rem & 63;
      const ushort_t* src =
          (lvl ? Bm : Bh) + (size_t)(ct * 64 + c) * N_DIM + k0 + kcc * 8;
      __builtin_amdgcn_global_load_lds(
          (const AS1 void*)src, (AS3 void*)(base + 1024 + t2 * 8), 16, 0, 0);
    }
  };

  f32x4 acc = (f32x4){0.f, 0.f, 0.f, 0.f};
  const int aO = kg * 128 + lrow * 8;
  const int bO = 1024 + kg * 512 + (w * 16 + lrow) * 8;

  stageS(0, kBase);
  asm volatile("s_waitcnt vmcnt(0)" ::: "memory");
  __builtin_amdgcn_s_barrier();
  for (int ks = 0; ks < 8; ++ks) {
    int cur = ks & 1;
    if (ks < 7) {
      stageS(cur ^ 1, kBase + (ks + 1) * 32);
      if (w < 2) asm volatile("s_waitcnt vmcnt(3)" ::: "memory");
      else       asm volatile("s_waitcnt vmcnt(2)" ::: "memory");
    } else {
      asm volatile("s_waitcnt vmcnt(0)" ::: "memory");
    }
    __builtin_amdgcn_s_barrier();
    __builtin_amdgcn_sched_barrier(0);
    const ushort_t* b = L + cur * 5120;
    bf16x8 a0 = *(const bf16x8*)&b[aO];
    bf16x8 a1 = *(const bf16x8*)&b[aO + 512];
    bf16x8 b0v = *(const bf16x8*)&b[bO];
    bf16x8 b1v = *(const bf16x8*)&b[bO + 2048];
    acc = __builtin_amdgcn_mfma_f32_16x16x32_bf16(a0, b0v, acc, 0, 0, 0);
    acc = __builtin_amdgcn_mfma_f32_16x16x32_bf16(a0, b1v, acc, 0, 0, 0);
    acc = __builtin_amdgcn_mfma_f32_16x16x32_bf16(a1, b0v, acc, 0, 0, 0);
    acc = __builtin_amdgcn_mfma_f32_16x16x32_bf16(a1, b1v, acc, 0, 0, 0);
    if (ks < 7) __builtin_amdgcn_s_barrier();
  }

  int rcol = ct * 64 + w * 16 + lrow;
#pragma unroll
  for (int j = 0; j < 4; ++j) {
    int q = rt * 16 + kg * 4 + j;
    atomicAdd(&Kv[q * 128 + rcol], acc[j]);
  }
}

// ---------------- causal convolution --------------------------------------
__global__ __launch_bounds__(256) void conv_k(const float* __restrict__ Kv,
    const float* __restrict__ u, float* __restrict__ y) {
  const int CT = 1024, CJ = 256, LCH = 1024;
  int t0 = blockIdx.x * CT;
  int l0 = blockIdx.y * LCH;
  if (l0 > t0 + CT - 1) return;
  __shared__ __align__(16) float Ks[CJ];
  __shared__ __align__(16) float us[CT + CJ + 8];
  int tid = threadIdx.x;
  float acc0 = 0.f, acc1 = 0.f, acc2 = 0.f, acc3 = 0.f;
  int ltEnd = l0 + LCH; if (ltEnd > t0 + CT) ltEnd = t0 + CT;
  for (int lt = l0; lt < ltEnd; lt += CJ) {
    __syncthreads();
    Ks[tid] = Kv[lt + tid];
    int ub = t0 - lt - (CJ - 1);
    for (int s = tid; s < CT + CJ + 4; s += 256) {
      int g = ub + s;
      us[s] = (g >= 0 && g < L_SEQ) ? u[g] : 0.f;
    }
    __syncthreads();
    const float4* u4 = (const float4*)us;
    float4 wa = u4[tid];
#pragma unroll 4
    for (int jb = 0; jb < CJ / 4; ++jb) {
      float4 wb = u4[tid + jb + 1];
      float4 k4 = *(const float4*)&Ks[CJ - 4 - (jb << 2)];
      acc0 += k4.w * wa.x + k4.z * wa.y + k4.y * wa.z + k4.x * wa.w;
      acc1 += k4.w * wa.y + k4.z * wa.z + k4.y * wa.w + k4.x * wb.x;
      acc2 += k4.w * wa.z + k4.z * wa.w + k4.y * wb.x + k4.x * wb.y;
      acc3 += k4.w * wa.w + k4.z * wb.x + k4.y * wb.y + k4.x * wb.z;
      wa = wb;
    }
  }
  int t = t0 + (tid << 2);
  atomicAdd(&y[t + 0], acc0);
  atomicAdd(&y[t + 1], acc1);
  atomicAdd(&y[t + 2], acc2);
  atomicAdd(&y[t + 3], acc3);
}

// ---------------- host ----------------

extern "C" void kernel_launch(void* const* d_in, const int* in_sizes, int n_in,
                              void* d_out, int out_size, void* d_ws, size_t ws_size,
                              hipStream_t stream) {
  const float* u  = (const float*)d_in[0];
  const float* A  = (const float*)d_in[1];
  const float* B  = (const float*)d_in[2];
  const float* Cm = (const float*)d_in[3];
  const float* ls = (const float*)d_in[4];
  float* y  = (float*)d_out;
  float* ws = (float*)d_ws;

  const int N = N_DIM;
  const size_t NN = (size_t)N * N;
  const size_t KR = (size_t)128 * N;
  float* b0 = ws;                     // E -> S
  float* b1 = b0 + NN;                // E2
  float* b2 = b1 + NN;                // S1
  float* Kv = b2 + NN;                // 128*128
  float* P  = Kv + L_SEQ;             // KS partial planes
  float* SP = P + (size_t)KS * NN;    // KS skinny partial planes (64x1024)
  ushort_t* setA = (ushort_t*)(SP + (size_t)KS * SPSTR);
  ushort_t* setB = setA + 4 * NN;
  ushort_t* setC = setB + 4 * NN;
  ushort_t* VTset = setC + 4 * NN;    // {H,M} each 128xN
  ushort_t* Wset = VTset + 2 * KR;

  hipMemsetAsync(Kv, 0, (size_t)L_SEQ * sizeof(float), stream);
  hipMemsetAsync(y,  0, (size_t)L_SEQ * sizeof(float), stream);

  dim3 g16(16, 16);
  dim3 gSq(16, 16, KS);     // squaring-only
  dim3 gFull(16, 20, KS);   // squaring + skinny split-K layers
  dim3 gRed(16, 17);        // reduce + skinny-reduce
  dim3 gSkF(16, 4, KS);     // final skinny-only
  dim3 gSkR(16, 1);         // final skinny reduce

  // E = (step/2)*A ; 4-plane splits -> setA
  k_scalesplit<<<g16, 256, 0, stream>>>(A, ls, b0, setA);
  // E2 = E*E : f32 -> b1, T-splits -> setB
  gemm4f<<<gSq, 256, 0, stream>>>(setA, setA + 2 * NN, P, nullptr, nullptr,
                                  SP, 0, 1);
  k_splitred<<<g16, 256, 0, stream>>>(P, nullptr, b1, setB, FW_F32 | FW_TSPLIT,
                                      nullptr, nullptr, 0, 0);
  // S1 = E + E2 : f32 -> b2, row-splits -> setA
  k_addsplit<<<NN / 1024, 256, 0, stream>>>(b0, b1, b2, setA);
  // S = S1*E2 + S1 : f32 S -> b0; Ab = 2S+I planes -> setC
  gemm4f<<<gSq, 256, 0, stream>>>(setA, setB + 2 * NN, P, nullptr, nullptr,
                                  SP, 0, 1);
  k_splitred<<<g16, 256, 0, stream>>>(P, b2, b0, setC,
                                      FW_F32 | FW_ADDD | FW_MKAB | FW_SPLIT | FW_TSPLIT,
                                      nullptr, nullptr, 0, 0);
  // VT row0 = split(Bb); W row0 = split(C)
  k_bbinit<<<260, 256, 0, stream>>>(VTset, Wset, b0, B, Cm, ls);

  // 13 fused steps: squaring + skinny split-K, then fused reduce.
  ushort_t* cur = setC;
  ushort_t* oth = setA;
  for (int e = 0; e < 13; ++e) {
    int right = (e < 7);
    int s = 1 << (right ? e : (e - 7));
    ushort_t* Ka = right ? VTset : Wset;
    const ushort_t* SkB = right ? cur : cur + 2 * NN;
    gemm4f<<<gFull, 256, 0, stream>>>(cur, cur + 2 * NN, P, SkB, Ka, SP, s, 1);
    int fl = (e == 12) ? FW_TSPLIT : (FW_SPLIT | FW_TSPLIT);
    k_splitred<<<gRed, 256, 0, stream>>>(P, nullptr, nullptr, oth, fl,
                                         SP, Ka, s, 0);
    ushort_t* tmp = cur; cur = oth; oth = tmp;
  }
  // final skinny-only: W rows 64->128 with Ab^8192 (T-splits of cur)
  gemm4f<<<gSkF, 256, 0, stream>>>(cur, cur + 2 * NN, P, cur + 2 * NN, Wset,
                                   SP, 64, 0);
  k_splitred<<<gSkR, 256, 0, stream>>>(P, nullptr, nullptr, nullptr, 0,
                                       SP, Wset, 64, 16);
  // K = W . V
  k_combine<<<dim3(8, 2, KS), 256, 0, stream>>>(Wset, VTset, Kv);
  // y = causal conv(K, u)
  conv_k<<<g16, 256, 0, stream>>>(Kv, u, y);
}

// Round 9
// 496.604 us; speedup vs baseline: 4.9273x; 1.0037x over previous
//
#include <hip/hip_runtime.h>
#include <hip/hip_bf16.h>
#include <math.h>

#define N_DIM 1024
#define L_SEQ 16384
#define KS 4
#define SPSTR 65536  // 64*1024 skinny partial plane stride

typedef unsigned short ushort_t;
typedef __bf16 bf16x8 __attribute__((ext_vector_type(8)));
typedef float f32x4 __attribute__((ext_vector_type(4)));

#define FW_F32 1
#define FW_SPLIT 2
#define FW_TSPLIT 4
#define FW_ADDD 8
#define FW_MKAB 16
#define FW_TPRE 32

#define AS1 __attribute__((address_space(1)))
#define AS3 __attribute__((address_space(3)))

__device__ __forceinline__ void split2(float v, ushort_t& h, ushort_t& m) {
  union { __bf16 b; ushort_t u; } c;
  __bf16 bh = (__bf16)v;
  float fh = (float)bh;
  c.b = bh; h = c.u;
  c.b = (__bf16)(v - fh); m = c.u;
}

// ---------------- fused scale + 4-plane split: E = h*A -------------------
__global__ __launch_bounds__(256) void k_scalesplit(const float* __restrict__ A,
    const float* __restrict__ ls, float* __restrict__ E,
    ushort_t* __restrict__ set) {
  const size_t NN = (size_t)N_DIM * N_DIM;
  float hs = 0.5f * expf(ls[0]);
  int t = threadIdx.x;
  int r0 = blockIdx.x * 64 + ((t >> 4) << 2);
  int c0 = blockIdx.y * 64 + ((t & 15) << 2);
  float v[4][4];
#pragma unroll
  for (int i = 0; i < 4; ++i) {
    float4 f = *(const float4*)&A[(size_t)(r0 + i) * N_DIM + c0];
    v[i][0] = hs * f.x; v[i][1] = hs * f.y; v[i][2] = hs * f.z; v[i][3] = hs * f.w;
    *(float4*)&E[(size_t)(r0 + i) * N_DIM + c0] =
        make_float4(v[i][0], v[i][1], v[i][2], v[i][3]);
  }
  ushort_t h[4][4], m[4][4];
#pragma unroll
  for (int i = 0; i < 4; ++i)
#pragma unroll
    for (int j = 0; j < 4; ++j) split2(v[i][j], h[i][j], m[i][j]);
#pragma unroll
  for (int i = 0; i < 4; ++i) {
    size_t o = (size_t)(r0 + i) * N_DIM + c0;
    *(ushort4*)&set[o] = make_ushort4(h[i][0], h[i][1], h[i][2], h[i][3]);
    *(ushort4*)&set[NN + o] = make_ushort4(m[i][0], m[i][1], m[i][2], m[i][3]);
  }
#pragma unroll
  for (int j = 0; j < 4; ++j) {
    size_t o = (size_t)(c0 + j) * N_DIM + r0;
    *(ushort4*)&set[2 * NN + o] = make_ushort4(h[0][j], h[1][j], h[2][j], h[3][j]);
    *(ushort4*)&set[3 * NN + o] = make_ushort4(m[0][j], m[1][j], m[2][j], m[3][j]);
  }
}

// blocks 0..255: VT row0 = split(step*(B + S@B)); blocks 256..259: W row0 = split(C)
__global__ __launch_bounds__(256) void k_bbinit(ushort_t* __restrict__ VTset,
    ushort_t* __restrict__ Wset, const float* __restrict__ S,
    const float* __restrict__ B, const float* __restrict__ Cm,
    const float* __restrict__ ls) {
  const size_t KR = (size_t)128 * N_DIM;
  int bx = blockIdx.x;
  if (bx >= 256) {
    int i = (bx - 256) * 256 + threadIdx.x;
    ushort_t h, m; split2(Cm[i], h, m);
    Wset[i] = h; Wset[KR + i] = m;
    return;
  }
  int row = bx * 4 + (threadIdx.x >> 6);
  int lane = threadIdx.x & 63;
  const float* Sr = S + (size_t)row * N_DIM;
  float sum = 0.f;
  for (int k = lane; k < N_DIM; k += 64) sum += Sr[k] * B[k];
  for (int off = 32; off; off >>= 1) sum += __shfl_down(sum, off);
  if (lane == 0) {
    float step = expf(ls[0]);
    float bb = step * (B[row] + sum);
    ushort_t h, m; split2(bb, h, m);
    VTset[row] = h; VTset[KR + row] = m;
  }
}

// ------- reduce KS partials; TPRE: T-splits of pre-add v -> set2; then (+D),
// optional mkAb, fp32/splits -> set; y>=16: skinny reduce.
__global__ __launch_bounds__(256) void k_splitred(
    const float* __restrict__ P,
    const float* __restrict__ D, float* __restrict__ Cf,
    ushort_t* __restrict__ set, int flags, ushort_t* __restrict__ set2,
    const float* __restrict__ SP, ushort_t* __restrict__ Ka,
    int s, int ybase) {
  const size_t NN = (size_t)N_DIM * N_DIM;
  const size_t KR = (size_t)128 * N_DIM;
  int t = threadIdx.x;
  int ey = blockIdx.y + ybase;
  if (ey >= 16) {
    int ct = blockIdx.x;
    for (int r0 = 0; r0 < s; r0 += 4) {
      int r = r0 + (t >> 6);
      int col = ct * 64 + (t & 63);
      if (r < s) {
        int o = r * 1024 + col;
        float v = SP[o] + SP[SPSTR + o] + SP[2 * SPSTR + o] + SP[3 * SPSTR + o];
        ushort_t h, m; split2(v, h, m);
        Ka[(size_t)(s + r) * N_DIM + col] = h;
        Ka[KR + (size_t)(s + r) * N_DIM + col] = m;
      }
    }
    return;
  }
  int r0 = blockIdx.x * 64 + ((t >> 4) << 2);
  int c0 = ey * 64 + ((t & 15) << 2);
  float v[4][4];
#pragma unroll
  for (int i = 0; i < 4; ++i) {
    float4 f = *(const float4*)&P[(size_t)(r0 + i) * N_DIM + c0];
    v[i][0] = f.x; v[i][1] = f.y; v[i][2] = f.z; v[i][3] = f.w;
  }
#pragma unroll
  for (int p = 1; p < KS; ++p) {
#pragma unroll
    for (int i = 0; i < 4; ++i) {
      float4 f = *(const float4*)&P[p * NN + (size_t)(r0 + i) * N_DIM + c0];
      v[i][0] += f.x; v[i][1] += f.y; v[i][2] += f.z; v[i][3] += f.w;
    }
  }
  if (flags & FW_TPRE) {
    ushort_t h[4][4], m[4][4];
#pragma unroll
    for (int i = 0; i < 4; ++i)
#pragma unroll
      for (int j = 0; j < 4; ++j) split2(v[i][j], h[i][j], m[i][j]);
#pragma unroll
    for (int j = 0; j < 4; ++j) {
      size_t o = (size_t)(c0 + j) * N_DIM + r0;
      *(ushort4*)&set2[2 * NN + o] = make_ushort4(h[0][j], h[1][j], h[2][j], h[3][j]);
      *(ushort4*)&set2[3 * NN + o] = make_ushort4(m[0][j], m[1][j], m[2][j], m[3][j]);
    }
  }
  if (flags & FW_ADDD) {
#pragma unroll
    for (int i = 0; i < 4; ++i) {
      float4 f = *(const float4*)&D[(size_t)(r0 + i) * N_DIM + c0];
      v[i][0] += f.x; v[i][1] += f.y; v[i][2] += f.z; v[i][3] += f.w;
    }
  }
  if (flags & FW_F32) {
#pragma unroll
    for (int i = 0; i < 4; ++i)
      *(float4*)&Cf[(size_t)(r0 + i) * N_DIM + c0] =
          make_float4(v[i][0], v[i][1], v[i][2], v[i][3]);
  }
  if (flags & FW_MKAB) {
#pragma unroll
    for (int i = 0; i < 4; ++i)
#pragma unroll
      for (int j = 0; j < 4; ++j)
        v[i][j] = 2.0f * v[i][j] + ((r0 + i) == (c0 + j) ? 1.0f : 0.0f);
  }
  if (flags & (FW_SPLIT | FW_TSPLIT)) {
    ushort_t h[4][4], m[4][4];
#pragma unroll
    for (int i = 0; i < 4; ++i)
#pragma unroll
      for (int j = 0; j < 4; ++j) split2(v[i][j], h[i][j], m[i][j]);
    if (flags & FW_SPLIT) {
#pragma unroll
      for (int i = 0; i < 4; ++i) {
        size_t o = (size_t)(r0 + i) * N_DIM + c0;
        *(ushort4*)&set[o] = make_ushort4(h[i][0], h[i][1], h[i][2], h[i][3]);
        *(ushort4*)&set[NN + o] = make_ushort4(m[i][0], m[i][1], m[i][2], m[i][3]);
      }
    }
    if (flags & FW_TSPLIT) {
#pragma unroll
      for (int j = 0; j < 4; ++j) {
        size_t o = (size_t)(c0 + j) * N_DIM + r0;
        *(ushort4*)&set[2 * NN + o] = make_ushort4(h[0][j], h[1][j], h[2][j], h[3][j]);
        *(ushort4*)&set[3 * NN + o] = make_ushort4(m[0][j], m[1][j], m[2][j], m[3][j]);
      }
    }
  }
}

// ---------------- fused: split-K squaring (128x128) + split-K skinny -------
// sqOn: y<8 -> squaring 128x128 tile, kChunk=256 -> P[z].
//       y>=8 -> skinny tile id=(y-8)*8+x, kChunk=256 -> SP[z].
// !sqOn: all blocks skinny, id = y*8+x.
__global__ __launch_bounds__(256) void gemm4f(
    const ushort_t* __restrict__ Qa, const ushort_t* __restrict__ Qbt,
    float* __restrict__ P, const ushort_t* __restrict__ SkB,
    const ushort_t* __restrict__ Ka, float* __restrict__ SP,
    int s, int sqOn) {
  const size_t NN = (size_t)N_DIM * N_DIM;
  const size_t KR = (size_t)128 * N_DIM;
  __shared__ __align__(16) ushort_t lds[32768];  // 64 KB
  int t = threadIdx.x;
  const int lane = t & 63, w = t >> 6;
  bool isSk = (!sqOn) || ((int)blockIdx.y >= 8);

  if (!isSk) {
    int m0 = blockIdx.x * 128, n0 = blockIdx.y * 128;
    int kz = blockIdx.z;
    const ushort_t* gA[2] = {Qa, Qa + NN};
    const ushort_t* gB[2] = {Qbt, Qbt + NN};
    int kBase = kz * 256;

    // buffer layout: [pl2][kc4][row128][8] for A (8192 us), B at +8192.
    auto stage = [&](int buf, int k0) {  // 8 load instrs per wave
      ushort_t* dst = lds + buf * 16384;
#pragma unroll
      for (int it = 0; it < 4; ++it) {
        int t2 = t + it * 256;
        int sl = t2 >> 7, row = t2 & 127;
        int pl = sl >> 2, kc = sl & 3;
        __builtin_amdgcn_global_load_lds(
            (const AS1 void*)(gA[pl] + (size_t)(m0 + row) * N_DIM + k0 + kc * 8),
            (AS3 void*)(dst + t2 * 8), 16, 0, 0);
        __builtin_amdgcn_global_load_lds(
            (const AS1 void*)(gB[pl] + (size_t)(n0 + row) * N_DIM + k0 + kc * 8),
            (AS3 void*)(dst + 8192 + t2 * 8), 16, 0, 0);
      }
    };

    f32x4 acc[4][4];
#pragma unroll
    for (int i = 0; i < 4; ++i)
#pragma unroll
      for (int j = 0; j < 4; ++j) acc[i][j] = (f32x4){0.f, 0.f, 0.f, 0.f};

    const int wm = (w >> 1) * 64, wn = (w & 1) * 64;
    const int lrow = lane & 15, kg = lane >> 4;
    const int aB0 = kg * 1024 + (wm + lrow) * 8;
    const int bB0 = 8192 + kg * 1024 + (wn + lrow) * 8;

    stage(0, kBase);
    asm volatile("s_waitcnt vmcnt(0)" ::: "memory");
    __builtin_amdgcn_s_barrier();
    for (int ks = 0; ks < 8; ++ks) {
      int cur = ks & 1;
      if (ks < 7) {
        stage(cur ^ 1, kBase + (ks + 1) * 32);
        asm volatile("s_waitcnt vmcnt(8)" ::: "memory");  // cur's 8 landed
      } else {
        asm volatile("s_waitcnt vmcnt(0)" ::: "memory");
      }
      __builtin_amdgcn_s_barrier();
      __builtin_amdgcn_sched_barrier(0);
      const ushort_t* buf = lds + cur * 16384;
      bf16x8 a[2][4], b[2][4];
#pragma unroll
      for (int pl = 0; pl < 2; ++pl) {
#pragma unroll
        for (int mi = 0; mi < 4; ++mi)
          a[pl][mi] = *(const bf16x8*)&buf[pl * 4096 + aB0 + mi * 128];
#pragma unroll
        for (int ni = 0; ni < 4; ++ni)
          b[pl][ni] = *(const bf16x8*)&buf[pl * 4096 + bB0 + ni * 128];
      }
#pragma unroll
      for (int mi = 0; mi < 4; ++mi)
#pragma unroll
        for (int ni = 0; ni < 4; ++ni) {
          f32x4 c = acc[mi][ni];
          c = __builtin_amdgcn_mfma_f32_16x16x32_bf16(a[0][mi], b[0][ni], c, 0, 0, 0);
          c = __builtin_amdgcn_mfma_f32_16x16x32_bf16(a[0][mi], b[1][ni], c, 0, 0, 0);
          c = __builtin_amdgcn_mfma_f32_16x16x32_bf16(a[1][mi], b[0][ni], c, 0, 0, 0);
          c = __builtin_amdgcn_mfma_f32_16x16x32_bf16(a[1][mi], b[1][ni], c, 0, 0, 0);
          acc[mi][ni] = c;
        }
      if (ks < 7) __builtin_amdgcn_s_barrier();
    }

    float* Pk = P + (size_t)kz * NN;
#pragma unroll
    for (int mi = 0; mi < 4; ++mi)
#pragma unroll
      for (int ni = 0; ni < 4; ++ni) {
        int rowb = m0 + wm + mi * 16 + kg * 4;
        int col = n0 + wn + ni * 16 + lrow;
#pragma unroll
        for (int j = 0; j < 4; ++j)
          Pk[(size_t)(rowb + j) * N_DIM + col] = acc[mi][ni][j];
      }
    return;
  }

  // ---- skinny Krylov, split-K (waves 0-1: 3 loads/stage, waves 2-3: 2) ----
  int id = sqOn ? ((int)blockIdx.y - 8) * 8 + (int)blockIdx.x
                : (int)blockIdx.y * 8 + (int)blockIdx.x;
  int kz = blockIdx.z;
  int rt = id >> 4, ct = id & 15;
  if (rt >= ((s + 15) >> 4)) return;
  const ushort_t* Ah = Ka;
  const ushort_t* Amm = Ka + KR;
  const ushort_t* Bh = SkB;
  const ushort_t* Bm = SkB + NN;
  const int lrow = lane & 15, kg = lane >> 4;
  int kBase = kz * 256;

  auto stageS = [&](int buf, int k0) {
    ushort_t* base = lds + buf * 5120;
    if (t < 128) {
      int lvl = t >> 6, rem = t & 63, kcc = rem >> 4, i = rem & 15;
      const ushort_t* src =
          (lvl ? Amm : Ah) + (size_t)(rt * 16 + i) * N_DIM + k0 + kcc * 8;
      __builtin_amdgcn_global_load_lds((const AS1 void*)src,
                                       (AS3 void*)(base + t * 8), 16, 0, 0);
    }
#pragma unroll
    for (int it2 = 0; it2 < 2; ++it2) {
      int t2 = t + it2 * 256;
      int lvl = t2 >> 8, rem = t2 & 255, kcc = rem >> 6, c = rem & 63;
      const ushort_t* src =
          (lvl ? Bm : Bh) + (size_t)(ct * 64 + c) * N_DIM + k0 + kcc * 8;
      __builtin_amdgcn_global_load_lds(
          (const AS1 void*)src, (AS3 void*)(base + 1024 + t2 * 8), 16, 0, 0);
    }
  };

  f32x4 acc = (f32x4){0.f, 0.f, 0.f, 0.f};
  const int aO = kg * 128 + lrow * 8;
  const int bO = 1024 + kg * 512 + (w * 16 + lrow) * 8;

  stageS(0, kBase);
  asm volatile("s_waitcnt vmcnt(0)" ::: "memory");
  __builtin_amdgcn_s_barrier();
  for (int ks2 = 0; ks2 < 8; ++ks2) {
    int cur = ks2 & 1;
    if (ks2 < 7) {
      stageS(cur ^ 1, kBase + (ks2 + 1) * 32);
      if (w < 2) asm volatile("s_waitcnt vmcnt(3)" ::: "memory");
      else       asm volatile("s_waitcnt vmcnt(2)" ::: "memory");
    } else {
      asm volatile("s_waitcnt vmcnt(0)" ::: "memory");
    }
    __builtin_amdgcn_s_barrier();
    __builtin_amdgcn_sched_barrier(0);
    const ushort_t* b = lds + cur * 5120;
    bf16x8 a0 = *(const bf16x8*)&b[aO];
    bf16x8 a1 = *(const bf16x8*)&b[aO + 512];
    bf16x8 b0v = *(const bf16x8*)&b[bO];
    bf16x8 b1v = *(const bf16x8*)&b[bO + 2048];
    acc = __builtin_amdgcn_mfma_f32_16x16x32_bf16(a0, b0v, acc, 0, 0, 0);
    acc = __builtin_amdgcn_mfma_f32_16x16x32_bf16(a0, b1v, acc, 0, 0, 0);
    acc = __builtin_amdgcn_mfma_f32_16x16x32_bf16(a1, b0v, acc, 0, 0, 0);
    acc = __builtin_amdgcn_mfma_f32_16x16x32_bf16(a1, b1v, acc, 0, 0, 0);
    if (ks2 < 7) __builtin_amdgcn_s_barrier();
  }

  float* sp = SP + (size_t)kz * SPSTR;
  int col = ct * 64 + w * 16 + lrow;
#pragma unroll
  for (int j = 0; j < 4; ++j) {
    int ir = rt * 16 + kg * 4 + j;
    if (ir < s) sp[ir * 1024 + col] = acc[j];
  }
}

// ---------------- combine: Kv[q*128+r] = W[q,:] . V[:,r] -------------------
__global__ __launch_bounds__(256) void k_combine(
    const ushort_t* __restrict__ Wset, const ushort_t* __restrict__ Vset,
    float* __restrict__ Kv) {
  const size_t KR = (size_t)128 * N_DIM;
  __shared__ __align__(16) ushort_t lds[2][5120];
  int t = threadIdx.x;
  int rt = blockIdx.x, ct = blockIdx.y, kz = blockIdx.z;
  int kBase = kz * 256;
  const ushort_t* Ah = Wset;
  const ushort_t* Amm = Wset + KR;
  const ushort_t* Bh = Vset;
  const ushort_t* Bm = Vset + KR;
  ushort_t* L = &lds[0][0];
  const int lane = t & 63, w = t >> 6;
  const int lrow = lane & 15, kg = lane >> 4;

  auto stageS = [&](int buf, int k0) {
    ushort_t* base = L + buf * 5120;
    if (t < 128) {
      int lvl = t >> 6, rem = t & 63, kcc = rem >> 4, i = rem & 15;
      const ushort_t* src =
          (lvl ? Amm : Ah) + (size_t)(rt * 16 + i) * N_DIM + k0 + kcc * 8;
      __builtin_amdgcn_global_load_lds((const AS1 void*)src,
                                       (AS3 void*)(base + t * 8), 16, 0, 0);
    }
#pragma unroll
    for (int it = 0; it < 2; ++it) {
      int t2 = t + it * 256;
      int lvl = t2 >> 8, rem = t2 & 255, kcc = rem >> 6, c = rem & 63;
      const ushort_t* src =
          (lvl ? Bm : Bh) + (size_t)(ct * 64 + c) * N_DIM + k0 + kcc * 8;
      __builtin_amdgcn_global_load_lds(
          (const AS1 void*)src, (AS3 void*)(base + 1024 + t2 * 8), 16, 0, 0);
    }
  };

  f32x4 acc = (f32x4){0.f, 0.f, 0.f, 0.f};
  const int aO = kg * 128 + lrow * 8;
  const int bO = 1024 + kg * 512 + (w * 16 + lrow) * 8;

  stageS(0, kBase);
  asm volatile("s_waitcnt vmcnt(0)" ::: "memory");
  __builtin_amdgcn_s_barrier();
  for (int ks = 0; ks < 8; ++ks) {
    int cur = ks & 1;
    if (ks < 7) {
      stageS(cur ^ 1, kBase + (ks + 1) * 32);
      if (w < 2) asm volatile("s_waitcnt vmcnt(3)" ::: "memory");
      else       asm volatile("s_waitcnt vmcnt(2)" ::: "memory");
    } else {
      asm volatile("s_waitcnt vmcnt(0)" ::: "memory");
    }
    __builtin_amdgcn_s_barrier();
    __builtin_amdgcn_sched_barrier(0);
    const ushort_t* b = L + cur * 5120;
    bf16x8 a0 = *(const bf16x8*)&b[aO];
    bf16x8 a1 = *(const bf16x8*)&b[aO + 512];
    bf16x8 b0v = *(const bf16x8*)&b[bO];
    bf16x8 b1v = *(const bf16x8*)&b[bO + 2048];
    acc = __builtin_amdgcn_mfma_f32_16x16x32_bf16(a0, b0v, acc, 0, 0, 0);
    acc = __builtin_amdgcn_mfma_f32_16x16x32_bf16(a0, b1v, acc, 0, 0, 0);
    acc = __builtin_amdgcn_mfma_f32_16x16x32_bf16(a1, b0v, acc, 0, 0, 0);
    acc = __builtin_amdgcn_mfma_f32_16x16x32_bf16(a1, b1v, acc, 0, 0, 0);
    if (ks < 7) __builtin_amdgcn_s_barrier();
  }

  int rcol = ct * 64 + w * 16 + lrow;
#pragma unroll
  for (int j = 0; j < 4; ++j) {
    int q = rt * 16 + kg * 4 + j;
    atomicAdd(&Kv[q * 128 + rcol], acc[j]);
  }
}

// ---------------- causal convolution --------------------------------------
__global__ __launch_bounds__(256) void conv_k(const float* __restrict__ Kv,
    const float* __restrict__ u, float* __restrict__ y) {
  const int CT = 1024, CJ = 256, LCH = 1024;
  int t0 = blockIdx.x * CT;
  int l0 = blockIdx.y * LCH;
  if (l0 > t0 + CT - 1) return;
  __shared__ __align__(16) float Ks[CJ];
  __shared__ __align__(16) float us[CT + CJ + 8];
  int tid = threadIdx.x;
  float acc0 = 0.f, acc1 = 0.f, acc2 = 0.f, acc3 = 0.f;
  int ltEnd = l0 + LCH; if (ltEnd > t0 + CT) ltEnd = t0 + CT;
  for (int lt = l0; lt < ltEnd; lt += CJ) {
    __syncthreads();
    Ks[tid] = Kv[lt + tid];
    int ub = t0 - lt - (CJ - 1);
    for (int s = tid; s < CT + CJ + 4; s += 256) {
      int g = ub + s;
      us[s] = (g >= 0 && g < L_SEQ) ? u[g] : 0.f;
    }
    __syncthreads();
    const float4* u4 = (const float4*)us;
    float4 wa = u4[tid];
#pragma unroll 4
    for (int jb = 0; jb < CJ / 4; ++jb) {
      float4 wb = u4[tid + jb + 1];
      float4 k4 = *(const float4*)&Ks[CJ - 4 - (jb << 2)];
      acc0 += k4.w * wa.x + k4.z * wa.y + k4.y * wa.z + k4.x * wa.w;
      acc1 += k4.w * wa.y + k4.z * wa.z + k4.y * wa.w + k4.x * wb.x;
      acc2 += k4.w * wa.z + k4.z * wa.w + k4.y * wb.x + k4.x * wb.y;
      acc3 += k4.w * wa.w + k4.z * wb.x + k4.y * wb.y + k4.x * wb.z;
      wa = wb;
    }
  }
  int t = t0 + (tid << 2);
  atomicAdd(&y[t + 0], acc0);
  atomicAdd(&y[t + 1], acc1);
  atomicAdd(&y[t + 2], acc2);
  atomicAdd(&y[t + 3], acc3);
}

// ---------------- host ----------------

extern "C" void kernel_launch(void* const* d_in, const int* in_sizes, int n_in,
                              void* d_out, int out_size, void* d_ws, size_t ws_size,
                              hipStream_t stream) {
  const float* u  = (const float*)d_in[0];
  const float* A  = (const float*)d_in[1];
  const float* B  = (const float*)d_in[2];
  const float* Cm = (const float*)d_in[3];
  const float* ls = (const float*)d_in[4];
  float* y  = (float*)d_out;
  float* ws = (float*)d_ws;

  const int N = N_DIM;
  const size_t NN = (size_t)N * N;
  const size_t KR = (size_t)128 * N;
  float* b0 = ws;                     // E -> S
  float* b1 = b0 + NN;                // (spare)
  float* b2 = b1 + NN;                // S1
  float* Kv = b2 + NN;                // 128*128
  float* P  = Kv + L_SEQ;             // KS partial planes
  float* SP = P + (size_t)KS * NN;    // KS skinny partial planes (64x1024)
  ushort_t* setA = (ushort_t*)(SP + (size_t)KS * SPSTR);
  ushort_t* setB = setA + 4 * NN;
  ushort_t* setC = setB + 4 * NN;
  ushort_t* VTset = setC + 4 * NN;    // {H,M} each 128xN
  ushort_t* Wset = VTset + 2 * KR;

  hipMemsetAsync(Kv, 0, (size_t)L_SEQ * sizeof(float), stream);
  hipMemsetAsync(y,  0, (size_t)L_SEQ * sizeof(float), stream);

  dim3 g16(16, 16);
  dim3 gSq(8, 8, KS);       // squaring-only
  dim3 gFull(8, 16, KS);    // squaring + skinny split-K layers
  dim3 gRed(16, 17);        // reduce + skinny-reduce
  dim3 gSkF(8, 8, KS);      // final skinny-only
  dim3 gSkR(16, 1);         // final skinny reduce

  // E = (step/2)*A ; 4-plane splits -> setA
  k_scalesplit<<<g16, 256, 0, stream>>>(A, ls, b0, setA);
  // E2 = E*E partials; fused: T-splits(E2)->setB, S1=E2+E f32->b2, row-splits(S1)->setA
  gemm4f<<<gSq, 256, 0, stream>>>(setA, setA + 2 * NN, P, nullptr, nullptr,
                                  SP, 0, 1);
  k_splitred<<<g16, 256, 0, stream>>>(P, b0, b2, setA,
                                      FW_TPRE | FW_ADDD | FW_F32 | FW_SPLIT,
                                      setB, nullptr, nullptr, 0, 0);
  // S = S1*E2 + S1 : f32 S -> b0; Ab = 2S+I planes -> setC
  gemm4f<<<gSq, 256, 0, stream>>>(setA, setB + 2 * NN, P, nullptr, nullptr,
                                  SP, 0, 1);
  k_splitred<<<g16, 256, 0, stream>>>(P, b2, b0, setC,
                                      FW_F32 | FW_ADDD | FW_MKAB | FW_SPLIT | FW_TSPLIT,
                                      nullptr, nullptr, nullptr, 0, 0);
  // VT row0 = split(Bb); W row0 = split(C)
  k_bbinit<<<260, 256, 0, stream>>>(VTset, Wset, b0, B, Cm, ls);

  // 13 fused steps: squaring + skinny split-K, then fused reduce.
  ushort_t* cur = setC;
  ushort_t* oth = setA;
  for (int e = 0; e < 13; ++e) {
    int right = (e < 7);
    int s = 1 << (right ? e : (e - 7));
    ushort_t* Ka = right ? VTset : Wset;
    const ushort_t* SkB = right ? cur : cur + 2 * NN;
    gemm4f<<<gFull, 256, 0, stream>>>(cur, cur + 2 * NN, P, SkB, Ka, SP, s, 1);
    int fl = (e == 12) ? FW_TSPLIT : (FW_SPLIT | FW_TSPLIT);
    k_splitred<<<gRed, 256, 0, stream>>>(P, nullptr, nullptr, oth, fl, nullptr,
                                         SP, Ka, s, 0);
    ushort_t* tmp = cur; cur = oth; oth = tmp;
  }
  // final skinny-only: W rows 64->128 with Ab^8192 (T-splits of cur)
  gemm4f<<<gSkF, 256, 0, stream>>>(cur, cur + 2 * NN, P, cur + 2 * NN, Wset,
                                   SP, 64, 0);
  k_splitred<<<gSkR, 256, 0, stream>>>(P, nullptr, nullptr, nullptr, 0, nullptr,
                                       SP, Wset, 64, 16);
  // K = W . V
  k_combine<<<dim3(8, 2, KS), 256, 0, stream>>>(Wset, VTset, Kv);
  // y = causal conv(K, u)
  conv_k<<<g16, 256, 0, stream>>>(Kv, u, y);
}